// Round 1
// 4992.118 us; speedup vs baseline: 1.1412x; 1.1412x over previous
//
#include <hip/hip_runtime.h>
#include <math.h>

#define Bq 8
#define Sq 256
#define Hq 768
#define FFq 3072
#define NHq 12
#define MROWS (Bq*Sq)          /* 2048 */
#define BSH (Bq*Sq*Hq)         /* 1,572,864 floats */

typedef __attribute__((ext_vector_type(8))) short short8;
typedef __attribute__((ext_vector_type(4))) float float4v;

// ---------------------------------------------------------------------------
// bf16 split helpers
// ---------------------------------------------------------------------------
__device__ __forceinline__ unsigned short f2bf(float f) {
  unsigned u = __float_as_uint(f);
  return (unsigned short)((u + 0x7fffu + ((u >> 16) & 1u)) >> 16);
}
__device__ __forceinline__ float bf2f(unsigned short h) {
  return __uint_as_float(((unsigned)h) << 16);
}
__device__ __forceinline__ uint4 pack8(const unsigned short* s) {
  uint4 u;
  u.x = (unsigned)s[0] | ((unsigned)s[1] << 16);
  u.y = (unsigned)s[2] | ((unsigned)s[3] << 16);
  u.z = (unsigned)s[4] | ((unsigned)s[5] << 16);
  u.w = (unsigned)s[6] | ((unsigned)s[7] << 16);
  return u;
}

// Fragment-blocked bf16 plane addressing: matrix (rows R, inner dim K).
// 1KB block per (rowtile=row/16, kc=k/32); lane = (row&15) | quad<<4 holds
// 16B = 8 bf16 of k = quad*8..+7. KC = K/32. Returns BYTE offset.
__device__ __forceinline__ size_t fbaddr(int row, int col, int KC) {
  return ((((size_t)(row >> 4)) * KC + (col >> 5)) << 10)
       + ((size_t)(((row & 15) | (((col >> 3) & 3) << 4))) << 4)
       + (size_t)((col & 7) << 1);
}

__device__ __forceinline__ void dma16(const void* g, void* l) {
  __builtin_amdgcn_global_load_lds(
      (const __attribute__((address_space(1))) unsigned int*)g,
      (__attribute__((address_space(3))) unsigned int*)l, 16, 0, 0);
}

// Block-uniform predicate: does ANY sample select `code`?
__device__ __forceinline__ bool any_sel(const float* sel, int code) {
  bool need = false;
  #pragma unroll
  for (int i = 0; i < Bq; ++i) need |= (sel[i] == (float)code);
  return need;
}

// ---------------------------------------------------------------------------
// Weight prep: W fp32 [K][N] row-major -> FB16 planes over (rows=N, K) i.e.
// B-operand (k-major per column). grid (N/64, K/32, z-mats).
// Skipped entirely when no sample routed to `code` this part.
// ---------------------------------------------------------------------------
__global__ __launch_bounds__(256)
void prep_w(const float* __restrict__ Wg, char* __restrict__ planes,
            int K, int N, long sInElem, long sOutBytes,
            const float* __restrict__ sel, int code)
{
  if (code && !any_sel(sel, code)) return;
  const int z = blockIdx.z;
  const float* W = Wg + (size_t)z * sInElem;
  char* hi = planes + (size_t)z * sOutBytes;
  char* lo = hi + (size_t)K * N * 2;
  const int n0 = blockIdx.x * 64, k0 = blockIdx.y * 32;
  const int t = threadIdx.x;
  __shared__ __align__(16) float Ws[32][68];
  {
    int rowk = t >> 3, cc = (t & 7) * 8;
    const float* src = W + (size_t)(k0 + rowk) * N + n0 + cc;
    float4 A4 = ((const float4*)src)[0];
    float4 B4 = ((const float4*)src)[1];
    *(float4*)&Ws[rowk][cc] = A4;
    *(float4*)&Ws[rowk][cc + 4] = B4;
  }
  __syncthreads();
  const int nl = (t & 15) | ((t >> 6) << 4);   // 0..63
  const int k8 = (t >> 4) & 3;
  unsigned short hs[8], ls[8];
  #pragma unroll
  for (int j = 0; j < 8; ++j) {
    float v = Ws[k8 * 8 + j][nl];
    unsigned short h = f2bf(v);
    hs[j] = h;
    ls[j] = f2bf(v - bf2f(h));
  }
  const int ng = n0 + nl;
  size_t off = (((size_t)(ng >> 4)) * (K >> 5) + (k0 >> 5)) * 1024
             + (size_t)(((ng & 15) | (k8 << 4)) << 4);
  *(uint4*)(hi + off) = pack8(hs);
  *(uint4*)(lo + off) = pack8(ls);
}

// ---------------------------------------------------------------------------
// Split-bf16 MFMA GEMM. A planes FB16 (M,K); W planes FB16 (N,K) (pre-T).
// MODE 0: C=acc+bias (fp32, z-batched)   1: +resid fp32
//      2: gelu -> planes only            3: +resid from planes (hi+lo)
// MT=2 -> 64x64 tile, MT=4 -> 128x128. 256 threads, 4 waves in 2x2.
// Row tiles (64/128) never straddle a 256-row sample: block-level skip.
// ---------------------------------------------------------------------------
template<int MT, int MODE>
__global__ __launch_bounds__(256)
void gemm_fb(const char* __restrict__ Ahi, const char* __restrict__ Alo,
             const char* __restrict__ Wpl, long sW,
             const float* __restrict__ bias, long sBias,
             const float* __restrict__ residF,
             const char* __restrict__ Rhi, const char* __restrict__ Rlo,
             float* __restrict__ C, long sC,
             char* __restrict__ Phi, char* __restrict__ Plo,
             int N, int K,
             const float* __restrict__ sel, int code)
{
  constexpr int TILE = MT * 32;
  constexpr int NB = 2 * MT;                   // 1KB blocks per plane
  __shared__ __align__(16) char lds[TILE * 256];  // Ahi|Alo|Bhi|Blo
  const int arow0 = blockIdx.y * TILE, bcol0 = blockIdx.x * TILE;
  if (code && sel[arow0 >> 8] != (float)code) return;
  const int z = blockIdx.z;
  const char* whi = Wpl + (size_t)z * sW;
  const char* wlo = whi + (size_t)K * N * 2;
  const float* bz = bias + (size_t)z * sBias;
  float* Cz = (MODE == 2) ? nullptr : (C + (size_t)z * sC);
  const int tid = threadIdx.x, lane = tid & 63, wv = tid >> 6;
  const int wm = wv >> 1, wn = wv & 1;
  const int KC = K >> 5;
  const char* bases[4] = {Ahi, Alo, whi, wlo};
  const char* wbase = bases[wv];
  const int rt0 = ((wv < 2) ? arow0 : bcol0) >> 4;
  float4v acc[MT][MT];
  #pragma unroll
  for (int i = 0; i < MT; ++i)
    #pragma unroll
    for (int j = 0; j < MT; ++j)
      acc[i][j] = (float4v){0.f, 0.f, 0.f, 0.f};

  for (int kc = 0; kc < KC; ++kc) {
    #pragma unroll
    for (int j = 0; j < NB; ++j) {
      size_t g = ((((size_t)(rt0 + j)) * KC + kc) << 10) + (size_t)lane * 16;
      dma16(wbase + g, lds + (wv * NB + j) * 1024);
    }
    __syncthreads();
    short8 bh[MT], bl[MT];
    #pragma unroll
    for (int nt = 0; nt < MT; ++nt) {
      bh[nt] = *(const short8*)(lds + (4 * MT + wn * MT + nt) * 1024 + lane * 16);
      bl[nt] = *(const short8*)(lds + (6 * MT + wn * MT + nt) * 1024 + lane * 16);
    }
    #pragma unroll
    for (int mt = 0; mt < MT; ++mt) {
      short8 ah = *(const short8*)(lds + (wm * MT + mt) * 1024 + lane * 16);
      short8 al = *(const short8*)(lds + (2 * MT + wm * MT + mt) * 1024 + lane * 16);
      #pragma unroll
      for (int nt = 0; nt < MT; ++nt) {
        acc[mt][nt] = __builtin_amdgcn_mfma_f32_16x16x32_bf16(ah, bh[nt], acc[mt][nt], 0, 0, 0);
        acc[mt][nt] = __builtin_amdgcn_mfma_f32_16x16x32_bf16(ah, bl[nt], acc[mt][nt], 0, 0, 0);
        acc[mt][nt] = __builtin_amdgcn_mfma_f32_16x16x32_bf16(al, bh[nt], acc[mt][nt], 0, 0, 0);
      }
    }
    __syncthreads();
  }
  // epilogue: C layout col=lane&15, row=quad*4+reg
  const int qd = lane >> 4, cI = lane & 15;
  const int KCo = N >> 5;
  #pragma unroll
  for (int mt = 0; mt < MT; ++mt) {
    #pragma unroll
    for (int nt = 0; nt < MT; ++nt) {
      int row0 = arow0 + (wm * MT + mt) * 16 + qd * 4;
      int col  = bcol0 + (wn * MT + nt) * 16 + cI;
      float bv = bz[col];
      #pragma unroll
      for (int r = 0; r < 4; ++r) {
        int row = row0 + r;
        float v = acc[mt][nt][r] + bv;
        if (MODE == 1) v += residF[(size_t)row * N + col];
        if (MODE == 3) {
          size_t ra = fbaddr(row, col, KCo);
          v += bf2f(*(const unsigned short*)(Rhi + ra))
             + bf2f(*(const unsigned short*)(Rlo + ra));
        }
        if (MODE == 2) {
          v = 0.5f * v * (1.0f + erff(v * 0.70710678118654752f));
          unsigned short hb = f2bf(v);
          unsigned short lb = f2bf(v - bf2f(hb));
          size_t pa = fbaddr(row, col, KCo);
          *(unsigned short*)(Phi + pa) = hb;
          *(unsigned short*)(Plo + pa) = lb;
        } else {
          Cz[(size_t)row * N + col] = v;
        }
      }
    }
  }
}

// ---------------------------------------------------------------------------
// Attention (fp32 VALU) — scores, softmax, ctx(->planes). Per-sample skip.
// ---------------------------------------------------------------------------
__global__ __launch_bounds__(256)
void attn_scores(const float* __restrict__ q, const float* __restrict__ k,
                 const float* __restrict__ mask, float* __restrict__ sc,
                 const float* __restrict__ sel, int code)
{
  const int z = blockIdx.z;
  const int b = z / NHq, hh = z % NHq;
  if (code && sel[b] != (float)code) return;
  const long base = (long)b * Sq * Hq + hh * 64;
  const int im = blockIdx.y, in = blockIdx.x;
  const int tid = threadIdx.x;
  const int tx = tid & 15, ty = tid >> 4;
  __shared__ __align__(16) float Qs[16][68];
  __shared__ __align__(16) float Ks[16][68];
  float acc[4][4] = {};
  const int row = tid >> 2;
  const int kl = (tid & 3) << 2;
  for (int kt = 0; kt < 64; kt += 16) {
    float4 a4 = *(const float4*)(q + base + (long)(im * 64 + row) * Hq + kt + kl);
    Qs[kl + 0][row] = a4.x; Qs[kl + 1][row] = a4.y; Qs[kl + 2][row] = a4.z; Qs[kl + 3][row] = a4.w;
    float4 b4 = *(const float4*)(k + base + (long)(in * 64 + row) * Hq + kt + kl);
    Ks[kl + 0][row] = b4.x; Ks[kl + 1][row] = b4.y; Ks[kl + 2][row] = b4.z; Ks[kl + 3][row] = b4.w;
    __syncthreads();
    #pragma unroll
    for (int kk = 0; kk < 16; ++kk) {
      float a[4], bb[4];
      *(float4*)a = *(const float4*)&Qs[kk][ty * 4];
      *(float4*)bb = *(const float4*)&Ks[kk][tx * 4];
      #pragma unroll
      for (int i2 = 0; i2 < 4; ++i2)
        #pragma unroll
        for (int j2 = 0; j2 < 4; ++j2)
          acc[i2][j2] = fmaf(a[i2], bb[j2], acc[i2][j2]);
    }
    __syncthreads();
  }
  #pragma unroll
  for (int i2 = 0; i2 < 4; ++i2) {
    int ig = im * 64 + ty * 4 + i2;
    #pragma unroll
    for (int j2 = 0; j2 < 4; ++j2) {
      int jg = in * 64 + tx * 4 + j2;
      sc[(long)z * (Sq * Sq) + (long)ig * Sq + jg] = acc[i2][j2] * 0.125f + mask[b * Sq + jg];
    }
  }
}

__global__ __launch_bounds__(256)
void softmax256(float* __restrict__ sc, const float* __restrict__ sel, int code)
{
  const int wid = threadIdx.x >> 6, lane = threadIdx.x & 63;
  const long row = (long)blockIdx.x * 4 + wid;
  {
    // 4 rows per block all lie in one z (256 rows per z); b = z/12
    const int zb = (int)((blockIdx.x * 4) >> 8);
    if (code && sel[zb / NHq] != (float)code) return;
  }
  float* p = sc + row * Sq;
  float v[4];
  float m = -1e30f;
  #pragma unroll
  for (int t = 0; t < 4; ++t) { v[t] = p[lane + t * 64]; m = fmaxf(m, v[t]); }
  #pragma unroll
  for (int off = 32; off >= 1; off >>= 1) m = fmaxf(m, __shfl_xor(m, off));
  float s = 0.0f;
  #pragma unroll
  for (int t = 0; t < 4; ++t) { v[t] = expf(v[t] - m); s += v[t]; }
  #pragma unroll
  for (int off = 32; off >= 1; off >>= 1) s += __shfl_xor(s, off);
  #pragma unroll
  for (int t = 0; t < 4; ++t) p[lane + t * 64] = v[t] / s;
}

// ctx -> FB16 planes (over M=2048 rows, K=768)
__global__ __launch_bounds__(256)
void attn_ctx(const float* __restrict__ sc, const float* __restrict__ vv,
              char* __restrict__ Phi, char* __restrict__ Plo,
              const float* __restrict__ sel, int code)
{
  const int z = blockIdx.z;
  const int b = z / NHq, hh = z % NHq;
  if (code && sel[b] != (float)code) return;
  const float* P = sc + (long)z * (Sq * Sq);
  const float* V = vv + (long)b * Sq * Hq + hh * 64;
  const int im = blockIdx.y;
  const int tid = threadIdx.x;
  const int tx = tid & 15, ty = tid >> 4;
  __shared__ __align__(16) float Ps[16][68];
  __shared__ __align__(16) float Vs[16][64];
  float acc[4][4] = {};
  const int row = tid >> 2;
  const int kl = (tid & 3) << 2;
  const int vr = tid >> 4, vc = (tid & 15) << 2;
  for (int kt = 0; kt < Sq; kt += 16) {
    float4 a4 = *(const float4*)(P + (long)(im * 64 + row) * Sq + kt + kl);
    Ps[kl + 0][row] = a4.x; Ps[kl + 1][row] = a4.y; Ps[kl + 2][row] = a4.z; Ps[kl + 3][row] = a4.w;
    *(float4*)&Vs[vr][vc] = *(const float4*)(V + (long)(kt + vr) * Hq + vc);
    __syncthreads();
    #pragma unroll
    for (int kk = 0; kk < 16; ++kk) {
      float a[4], bb[4];
      *(float4*)a = *(const float4*)&Ps[kk][ty * 4];
      *(float4*)bb = *(const float4*)&Vs[kk][tx * 4];
      #pragma unroll
      for (int i2 = 0; i2 < 4; ++i2)
        #pragma unroll
        for (int j2 = 0; j2 < 4; ++j2)
          acc[i2][j2] = fmaf(a[i2], bb[j2], acc[i2][j2]);
    }
    __syncthreads();
  }
  const int c0 = hh * 64 + tx * 4;
  #pragma unroll
  for (int i2 = 0; i2 < 4; ++i2) {
    int grow = b * 256 + im * 64 + ty * 4 + i2;
    unsigned short h[4], l[4];
    #pragma unroll
    for (int j2 = 0; j2 < 4; ++j2) {
      float x = acc[i2][j2];
      h[j2] = f2bf(x);
      l[j2] = f2bf(x - bf2f(h[j2]));
    }
    size_t pa = fbaddr(grow, c0, 24);
    uint2 uh; uh.x = (unsigned)h[0] | ((unsigned)h[1] << 16); uh.y = (unsigned)h[2] | ((unsigned)h[3] << 16);
    uint2 ul; ul.x = (unsigned)l[0] | ((unsigned)l[1] << 16); ul.y = (unsigned)l[2] | ((unsigned)l[3] << 16);
    *(uint2*)(Phi + pa) = uh;
    *(uint2*)(Plo + pa) = ul;
  }
}

// ---------------------------------------------------------------------------
// LayerNorm (row of 768) -> FB16 planes; per-sample skip (row>>8 = sample)
// ---------------------------------------------------------------------------
__global__ __launch_bounds__(256)
void ln_fb(const float* __restrict__ x, char* __restrict__ yh, char* __restrict__ yl,
           const float* __restrict__ g, const float* __restrict__ bta,
           const float* __restrict__ sel, int code)
{
  const int row = blockIdx.x, t = threadIdx.x;
  if (code && sel[row >> 8] != (float)code) return;
  const float* xr = x + (size_t)row * Hq;
  __shared__ float xs[Hq];
  __shared__ float ss[4], qq[4];
  float a = xr[t], b = xr[t + 256], c = xr[t + 512];
  xs[t] = a; xs[t + 256] = b; xs[t + 512] = c;
  float s = a + b + c;
  float q2 = a * a + b * b + c * c;
  #pragma unroll
  for (int off = 32; off >= 1; off >>= 1) { s += __shfl_xor(s, off); q2 += __shfl_xor(q2, off); }
  const int wid = t >> 6, lane = t & 63;
  if (lane == 0) { ss[wid] = s; qq[wid] = q2; }
  __syncthreads();
  s = ss[0] + ss[1] + ss[2] + ss[3];
  q2 = qq[0] + qq[1] + qq[2] + qq[3];
  const float mean = s * (1.0f / 768.0f);
  const float var = q2 * (1.0f / 768.0f) - mean * mean;
  const float r = rsqrtf(var + 1e-12f);
  if (t < 96) {
    const int c0 = t * 8;
    unsigned short hs[8], ls[8];
    #pragma unroll
    for (int j = 0; j < 8; ++j) {
      float y = (xs[c0 + j] - mean) * r * g[c0 + j] + bta[c0 + j];
      hs[j] = f2bf(y);
      ls[j] = f2bf(y - bf2f(hs[j]));
    }
    size_t pa = fbaddr(row, c0, 24);
    *(uint4*)(yh + pa) = pack8(hs);
    *(uint4*)(yl + pa) = pack8(ls);
  }
}

// ---------------------------------------------------------------------------
// h0: copy fp32 + emit planes. grid 768 x 256.
// ---------------------------------------------------------------------------
__global__ __launch_bounds__(256)
void h0split(const float* __restrict__ src, float* __restrict__ hout,
             char* __restrict__ hh, char* __restrict__ hl)
{
  const int idx = blockIdx.x * 256 + threadIdx.x;
  const int row = idx / 96, c0 = (idx % 96) * 8;
  const float* p = src + (size_t)row * Hq + c0;
  float v[8];
  *(float4*)&v[0] = ((const float4*)p)[0];
  *(float4*)&v[4] = ((const float4*)p)[1];
  float* o = hout + (size_t)row * Hq + c0;
  ((float4*)o)[0] = *(float4*)&v[0];
  ((float4*)o)[1] = *(float4*)&v[4];
  unsigned short hs[8], ls[8];
  #pragma unroll
  for (int j = 0; j < 8; ++j) { hs[j] = f2bf(v[j]); ls[j] = f2bf(v[j] - bf2f(hs[j])); }
  size_t pa = fbaddr(row, c0, 24);
  *(uint4*)(hh + pa) = pack8(hs);
  *(uint4*)(hl + pa) = pack8(ls);
}

// ---------------------------------------------------------------------------
// Select: h = (code==1)?base:(code==2)?large:h ; refresh fp32 + planes
// ---------------------------------------------------------------------------
__global__ __launch_bounds__(256)
void select_fb(float* __restrict__ hout, char* __restrict__ hh, char* __restrict__ hl,
               const char* __restrict__ bh, const char* __restrict__ bl,
               const char* __restrict__ gh, const char* __restrict__ gl,
               const float* __restrict__ sel)
{
  const int idx = blockIdx.x * 256 + threadIdx.x;
  const int row = idx / 96, c0 = (idx % 96) * 8;
  const int b = row >> 8;
  const float code = sel[b];
  const size_t pa = fbaddr(row, c0, 24);
  float v[8];
  if (code == 1.0f || code == 2.0f) {
    const char* sh = (code == 1.0f) ? bh : gh;
    const char* sl = (code == 1.0f) ? bl : gl;
    uint4 H = *(const uint4*)(sh + pa);
    uint4 L = *(const uint4*)(sl + pa);
    const unsigned* hw = (const unsigned*)&H;
    const unsigned* lw = (const unsigned*)&L;
    #pragma unroll
    for (int j = 0; j < 8; ++j) {
      unsigned short hb = (unsigned short)(hw[j >> 1] >> ((j & 1) * 16));
      unsigned short lb = (unsigned short)(lw[j >> 1] >> ((j & 1) * 16));
      v[j] = bf2f(hb) + bf2f(lb);
    }
  } else {
    const float* p = hout + (size_t)row * Hq + c0;
    *(float4*)&v[0] = ((const float4*)p)[0];
    *(float4*)&v[4] = ((const float4*)p)[1];
  }
  float* o = hout + (size_t)row * Hq + c0;
  ((float4*)o)[0] = *(float4*)&v[0];
  ((float4*)o)[1] = *(float4*)&v[4];
  unsigned short hs[8], ls[8];
  #pragma unroll
  for (int j = 0; j < 8; ++j) { hs[j] = f2bf(v[j]); ls[j] = f2bf(v[j] - bf2f(hs[j])); }
  *(uint4*)(hh + pa) = pack8(hs);
  *(uint4*)(hl + pa) = pack8(ls);
}

// ---------------------------------------------------------------------------
// Router — with inactive-sample early-out (writes padded outputs directly)
// ---------------------------------------------------------------------------
__global__ __launch_bounds__(256)
void router_kernel(const float* __restrict__ h,
                   const float* __restrict__ A_pw, const float* __restrict__ A_pb,
                   const float* __restrict__ A_cw, const float* __restrict__ A_cb,
                   const float* __restrict__ E_pw, const float* __restrict__ E_pb,
                   const float* __restrict__ E_cw, const float* __restrict__ E_cb,
                   float* __restrict__ active,
                   float* __restrict__ probs_out, float* __restrict__ acts_out,
                   float* __restrict__ exit_logits, float* __restrict__ exit_part,
                   float* __restrict__ sel_code, int part)
{
  const int b = blockIdx.x, t = threadIdx.x;
  const bool act = (active[b] != 0.0f);
  if (!act) {
    if (t == 0) {
      probs_out[b * 3 + 0] = 1.0f;
      probs_out[b * 3 + 1] = 1.0f;
      probs_out[b * 3 + 2] = 1.0f;
      acts_out[b] = 0.0f;
      sel_code[b] = 0.0f;
    }
    return;
  }
  __shared__ float hrow[Hq], pooled[Hq];
  __shared__ float red[3][256];
  __shared__ float resL[3];
  for (int c = t; c < Hq; c += 256) hrow[c] = h[(long)b * Sq * Hq + c];
  __syncthreads();
  for (int c = t; c < Hq; c += 256) {
    float s = A_pb[c];
    for (int r = 0; r < Hq; ++r) s = fmaf(hrow[r], A_pw[(long)r * Hq + c], s);
    pooled[c] = tanhf(s);
  }
  __syncthreads();
  {
    float p0 = 0, p1 = 0, p2 = 0;
    for (int r = t; r < Hq; r += 256) {
      float p = pooled[r];
      p0 = fmaf(p, A_cw[r * 3 + 0], p0);
      p1 = fmaf(p, A_cw[r * 3 + 1], p1);
      p2 = fmaf(p, A_cw[r * 3 + 2], p2);
    }
    red[0][t] = p0; red[1][t] = p1; red[2][t] = p2;
  }
  __syncthreads();
  for (int s2 = 128; s2 > 0; s2 >>= 1) {
    if (t < s2) { red[0][t] += red[0][t + s2]; red[1][t] += red[1][t + s2]; red[2][t] += red[2][t + s2]; }
    __syncthreads();
  }
  if (t == 0) { resL[0] = red[0][0] + A_cb[0]; resL[1] = red[1][0] + A_cb[1]; resL[2] = red[2][0] + A_cb[2]; }
  __syncthreads();
  for (int c = t; c < Hq; c += 256) {
    float s = E_pb[c];
    for (int r = 0; r < Hq; ++r) s = fmaf(hrow[r], E_pw[(long)r * Hq + c], s);
    pooled[c] = tanhf(s);
  }
  __syncthreads();
  {
    float p0 = 0, p1 = 0;
    for (int r = t; r < Hq; r += 256) {
      float p = pooled[r];
      p0 = fmaf(p, E_cw[r * 2 + 0], p0);
      p1 = fmaf(p, E_cw[r * 2 + 1], p1);
    }
    red[0][t] = p0; red[1][t] = p1;
  }
  __syncthreads();
  for (int s2 = 128; s2 > 0; s2 >>= 1) {
    if (t < s2) { red[0][t] += red[0][t + s2]; red[1][t] += red[1][t + s2]; }
    __syncthreads();
  }
  if (t == 0) {
    const float e0 = red[0][0] + E_cb[0], e1 = red[1][0] + E_cb[1];
    const float l0 = resL[0], l1 = resL[1], l2 = resL[2];
    int action = 0; float bv = l0;
    if (l1 > bv) { bv = l1; action = 1; }
    if (l2 > bv) { bv = l2; action = 2; }
    const float x0 = expf(l0 - bv), x1 = expf(l1 - bv), x2 = expf(l2 - bv);
    const float ssum = x0 + x1 + x2;
    probs_out[b * 3 + 0] = x0 / ssum;
    probs_out[b * 3 + 1] = x1 / ssum;
    probs_out[b * 3 + 2] = x2 / ssum;
    acts_out[b] = (float)action;
    if (action == 0) {
      exit_logits[b * 2 + 0] = e0;
      exit_logits[b * 2 + 1] = e1;
      exit_part[b] = (float)part;
    }
    sel_code[b] = (float)action;
    active[b] = (action != 0) ? 1.0f : 0.0f;
  }
}

__global__ __launch_bounds__(64)
void init_kernel(float* __restrict__ active, float* __restrict__ exit_logits,
                 float* __restrict__ exit_part)
{
  const int t = threadIdx.x;
  if (t < 8) { active[t] = 1.0f; exit_part[t] = -1.0f; }
  if (t < 16) exit_logits[t] = 0.0f;
}

// ---------------------------------------------------------------------------
struct WS {
  float* sel;
  char* wjit;                       // 9,437,184 B (one matrix / 4 attn mats)
  float* q; float* k; float* v;     // fp32 scratch; q reused as x1 planes,
                                    // k reused as ctx planes then FFN2-out fp32
  float* big;                       // scores fp32 -> O-out fp32 -> ffn planes
  const float* mask;
  float* hout;                      // fp32 h in d_out
};

#define MATATTN 2359296L            /* bytes: 768*768*4 (one plane pair) */
#define ACTPL   3145728L            /* bytes per activation plane (2048*768*2) */

static void run_layer_fb(const char* xhi, const char* xlo,
                         const float* residF, const char* rOhi, const char* rOlo,
                         char* outhi, char* outlo,
                         const float* aw, const float* ab,
                         const float* lng, const float* lnb,
                         const float* wi, const float* bi,
                         const float* wo, const float* bo,
                         const WS& W, int code, hipStream_t s)
{
  // attention weights -> planes (Wq,Wk,Wv,Wo)
  prep_w<<<dim3(12, 24, 4), 256, 0, s>>>(aw, W.wjit, 768, 768, 589824L, MATATTN,
                                         W.sel, code);
  // QKV (z=3)
  gemm_fb<2, 0><<<dim3(12, 32, 3), 256, 0, s>>>(
      xhi, xlo, W.wjit, MATATTN, ab, 768, nullptr, nullptr, nullptr,
      W.q, (long)BSH, nullptr, nullptr, 768, 768, W.sel, code);
  attn_scores<<<dim3(4, 4, 96), 256, 0, s>>>(W.q, W.k, W.mask, W.big, W.sel, code);
  softmax256<<<dim3(96 * 256 / 4), 256, 0, s>>>(W.big, W.sel, code);
  char* cph = (char*)W.k;             // ctx planes overwrite k (dead)
  char* cpl = cph + ACTPL;
  attn_ctx<<<dim3(1, 4, 96), 256, 0, s>>>(W.big, W.v, cph, cpl, W.sel, code);
  float* t0 = W.big;                  // O out fp32 (scores dead)
  if (residF) {
    gemm_fb<2, 1><<<dim3(12, 32), 256, 0, s>>>(
        cph, cpl, W.wjit + 3 * MATATTN, 0, ab + 3 * 768, 0, residF, nullptr, nullptr,
        t0, 0, nullptr, nullptr, 768, 768, W.sel, code);
  } else {
    gemm_fb<2, 3><<<dim3(12, 32), 256, 0, s>>>(
        cph, cpl, W.wjit + 3 * MATATTN, 0, ab + 3 * 768, 0, nullptr, rOhi, rOlo,
        t0, 0, nullptr, nullptr, 768, 768, W.sel, code);
  }
  char* x1h = (char*)W.q;             // x1 planes overwrite q (dead)
  char* x1l = x1h + ACTPL;
  ln_fb<<<MROWS, 256, 0, s>>>(t0, x1h, x1l, lng, lnb, W.sel, code);
  // FFN1 (gelu -> planes in big; t0 dead after ln)
  prep_w<<<dim3(48, 24, 1), 256, 0, s>>>(wi, W.wjit, 768, 3072, 0, 0, W.sel, code);
  char* fph = (char*)W.big;
  char* fpl = fph + 2048L * 3072 * 2;
  gemm_fb<4, 2><<<dim3(24, 16), 256, 0, s>>>(
      x1h, x1l, W.wjit, 0, bi, 0, nullptr, nullptr, nullptr,
      nullptr, 0, fph, fpl, 3072, 768, W.sel, code);
  // FFN2 (+resid from x1 planes) -> fp32 in k region (ctx planes dead)
  prep_w<<<dim3(12, 96, 1), 256, 0, s>>>(wo, W.wjit, 3072, 768, 0, 0, W.sel, code);
  float* t2 = W.k;
  gemm_fb<2, 3><<<dim3(12, 32), 256, 0, s>>>(
      fph, fpl, W.wjit, 0, bo, 0, nullptr, x1h, x1l,
      t2, 0, nullptr, nullptr, 768, 3072, W.sel, code);
  ln_fb<<<MROWS, 256, 0, s>>>(t2, outhi, outlo, lng + 768, lnb + 768, W.sel, code);
}

extern "C" void kernel_launch(void* const* d_in, const int* in_sizes, int n_in,
                              void* d_out, int out_size, void* d_ws, size_t ws_size,
                              hipStream_t stream)
{
  (void)in_sizes; (void)n_in; (void)out_size; (void)ws_size;
  const float* hidden   = (const float*)d_in[0];
  const float* mask     = (const float*)d_in[1];
  const float* L_attn_w = (const float*)d_in[2];
  const float* L_attn_b = (const float*)d_in[3];
  const float* L_ln_g   = (const float*)d_in[4];
  const float* L_ln_b   = (const float*)d_in[5];
  const float* L_wi     = (const float*)d_in[6];
  const float* L_bi     = (const float*)d_in[7];
  const float* L_wo     = (const float*)d_in[8];
  const float* L_bo     = (const float*)d_in[9];
  const float* S_attn_w = (const float*)d_in[10];
  const float* S_attn_b = (const float*)d_in[11];
  const float* S_ln_g   = (const float*)d_in[12];
  const float* S_ln_b   = (const float*)d_in[13];
  const float* S_wi     = (const float*)d_in[14];
  const float* S_bi     = (const float*)d_in[15];
  const float* S_wo     = (const float*)d_in[16];
  const float* S_bo     = (const float*)d_in[17];
  const float* E_pw     = (const float*)d_in[18];
  const float* E_pb     = (const float*)d_in[19];
  const float* E_cw     = (const float*)d_in[20];
  const float* E_cb     = (const float*)d_in[21];
  const float* A_pw     = (const float*)d_in[22];
  const float* A_pb     = (const float*)d_in[23];
  const float* A_cw     = (const float*)d_in[24];
  const float* A_cb     = (const float*)d_in[25];

  float* out = (float*)d_out;
  float* h      = out;
  float* active = out + 1572864;
  float* probs  = out + 1572872;
  float* acts   = out + 1573016;
  float* exitl  = out + 1573064;
  float* exitp  = out + 1573080;

  char* ws = (char*)d_ws;
  float* sel    = (float*)ws;                       // 256 B
  char* wjit    = ws + 256;                         // 9,437,184
  char* qreg    = wjit + 9437184;                   // 6,291,456
  char* kreg    = qreg + 6291456;                   // 6,291,456
  char* vreg    = kreg + 6291456;                   // 6,291,456
  char* bigc    = vreg + 6291456;                   // 25,165,824
  char* basepl  = bigc + 25165824;                  // 6,291,456
  char* largepl = basepl + 6291456;                 // 6,291,456
  char* hpl     = largepl + 6291456;                // 6,291,456  (total ~72.3 MB)

  WS W;
  W.sel = sel; W.wjit = wjit;
  W.q = (float*)qreg; W.k = (float*)kreg; W.v = (float*)vreg;
  W.big = (float*)bigc; W.mask = mask; W.hout = h;

  init_kernel<<<dim3(1), 64, 0, stream>>>(active, exitl, exitp);
  h0split<<<dim3(768), 256, 0, stream>>>(hidden, h, hpl, hpl + ACTPL);

  for (int i = 0; i < 6; ++i) {
    router_kernel<<<dim3(Bq), 256, 0, stream>>>(
        h, A_pw, A_pb, A_cw, A_cb,
        E_pw + (long)i * Hq * Hq, E_pb + i * Hq,
        E_cw + (long)i * Hq * 2, E_cb + i * 2,
        active, probs + i * 24, acts + i * 8, exitl, exitp, sel, i);
    // base = small layer i on h — only needed where sel==1
    run_layer_fb(hpl, hpl + ACTPL, h, nullptr, nullptr, basepl, basepl + ACTPL,
                 S_attn_w + (long)i * 4 * Hq * Hq, S_attn_b + (long)i * 4 * Hq,
                 S_ln_g + (long)i * 2 * Hq, S_ln_b + (long)i * 2 * Hq,
                 S_wi + (long)i * Hq * FFq, S_bi + (long)i * FFq,
                 S_wo + (long)i * FFq * Hq, S_bo + (long)i * Hq, W, 1, stream);
    // large = layers 2i, 2i+1 on h — only needed where sel==2
    const int j0 = 2 * i, j1 = 2 * i + 1;
    run_layer_fb(hpl, hpl + ACTPL, h, nullptr, nullptr, largepl, largepl + ACTPL,
                 L_attn_w + (long)j0 * 4 * Hq * Hq, L_attn_b + (long)j0 * 4 * Hq,
                 L_ln_g + (long)j0 * 2 * Hq, L_ln_b + (long)j0 * 2 * Hq,
                 L_wi + (long)j0 * Hq * FFq, L_bi + (long)j0 * FFq,
                 L_wo + (long)j0 * FFq * Hq, L_bo + (long)j0 * Hq, W, 2, stream);
    run_layer_fb(largepl, largepl + ACTPL, nullptr, largepl, largepl + ACTPL,
                 largepl, largepl + ACTPL,
                 L_attn_w + (long)j1 * 4 * Hq * Hq, L_attn_b + (long)j1 * 4 * Hq,
                 L_ln_g + (long)j1 * 2 * Hq, L_ln_b + (long)j1 * 2 * Hq,
                 L_wi + (long)j1 * Hq * FFq, L_bi + (long)j1 * FFq,
                 L_wo + (long)j1 * FFq * Hq, L_bo + (long)j1 * Hq, W, 2, stream);
    select_fb<<<dim3(768), 256, 0, stream>>>(h, hpl, hpl + ACTPL,
                                             basepl, basepl + ACTPL,
                                             largepl, largepl + ACTPL, sel);
  }
}

// Round 2
// 4034.078 us; speedup vs baseline: 1.4123x; 1.2375x over previous
//
#include <hip/hip_runtime.h>
#include <math.h>

#define Bq 8
#define Sq 256
#define Hq 768
#define FFq 3072
#define NHq 12
#define MROWS (Bq*Sq)          /* 2048 */
#define BSH (Bq*Sq*Hq)         /* 1,572,864 floats */

#define MATATTN 2359296L       /* bytes: one 768x768 plane pair (hi+lo) */
#define PLH     3145728L       /* bytes: one 2048x768 bf16 plane (hi or lo) */
#define PLPAIR  6291456L       /* hi+lo pair for a 2048x768 activation */
#define SLOTW   28311552L      /* per-layer weight planes: attn(4)+wi+wo */
#define WIOFF   9437184L
#define WOOFF   18874368L

typedef __attribute__((ext_vector_type(8))) short short8;
typedef __attribute__((ext_vector_type(4))) float float4v;

// ---------------------------------------------------------------------------
// bf16 split helpers
// ---------------------------------------------------------------------------
__device__ __forceinline__ unsigned short f2bf(float f) {
  unsigned u = __float_as_uint(f);
  return (unsigned short)((u + 0x7fffu + ((u >> 16) & 1u)) >> 16);
}
__device__ __forceinline__ float bf2f(unsigned short h) {
  return __uint_as_float(((unsigned)h) << 16);
}
__device__ __forceinline__ uint4 pack8(const unsigned short* s) {
  uint4 u;
  u.x = (unsigned)s[0] | ((unsigned)s[1] << 16);
  u.y = (unsigned)s[2] | ((unsigned)s[3] << 16);
  u.z = (unsigned)s[4] | ((unsigned)s[5] << 16);
  u.w = (unsigned)s[6] | ((unsigned)s[7] << 16);
  return u;
}

// Fragment-blocked bf16 plane addressing (rows R, inner dim K). 1KB block per
// (rowtile=row/16, kc=k/32); lane = (row&15)|quad<<4 holds 16B = 8 bf16.
__device__ __forceinline__ size_t fbaddr(int row, int col, int KC) {
  return ((((size_t)(row >> 4)) * KC + (col >> 5)) << 10)
       + ((size_t)(((row & 15) | (((col >> 3) & 3) << 4))) << 4)
       + (size_t)((col & 7) << 1);
}

__device__ __forceinline__ void dma16(const void* g, void* l) {
  __builtin_amdgcn_global_load_lds(
      (const __attribute__((address_space(1))) unsigned int*)g,
      (__attribute__((address_space(3))) unsigned int*)l, 16, 0, 0);
}

__device__ __forceinline__ bool any_sel(const float* sel, int code) {
  bool need = false;
  #pragma unroll
  for (int i = 0; i < Bq; ++i) need |= (sel[i] == (float)code);
  return need;
}

// ---------------------------------------------------------------------------
// Weight prep: W fp32 [K][N] -> FB16 planes (rows=N, inner=K).
// z maps to (group, mat): in = Wg + gq*sInGroup + mq*sInMat (elements),
// out = planes + gq*sOutGroup + mq*sOutMat (bytes). grid (N/64, K/32, z).
// ---------------------------------------------------------------------------
__global__ __launch_bounds__(256)
void prep_w(const float* __restrict__ Wg, char* __restrict__ planes,
            int K, int N, long sInMat, long sInGroup, int zPerGroup,
            long sOutMat, long sOutGroup,
            const float* __restrict__ sel, int code)
{
  if (code && !any_sel(sel, code)) return;
  const int z = blockIdx.z;
  const int gq = z / zPerGroup, mq = z % zPerGroup;
  const float* W = Wg + (size_t)gq * sInGroup + (size_t)mq * sInMat;
  char* hi = planes + (size_t)gq * sOutGroup + (size_t)mq * sOutMat;
  char* lo = hi + (size_t)K * N * 2;
  const int n0 = blockIdx.x * 64, k0 = blockIdx.y * 32;
  const int t = threadIdx.x;
  __shared__ __align__(16) float Ws[32][68];
  {
    int rowk = t >> 3, cc = (t & 7) * 8;
    const float* src = W + (size_t)(k0 + rowk) * N + n0 + cc;
    float4 A4 = ((const float4*)src)[0];
    float4 B4 = ((const float4*)src)[1];
    *(float4*)&Ws[rowk][cc] = A4;
    *(float4*)&Ws[rowk][cc + 4] = B4;
  }
  __syncthreads();
  const int nl = (t & 15) | ((t >> 6) << 4);   // 0..63
  const int k8 = (t >> 4) & 3;
  unsigned short hs[8], ls[8];
  #pragma unroll
  for (int j = 0; j < 8; ++j) {
    float v = Ws[k8 * 8 + j][nl];
    unsigned short h = f2bf(v);
    hs[j] = h;
    ls[j] = f2bf(v - bf2f(h));
  }
  const int ng = n0 + nl;
  size_t off = (((size_t)(ng >> 4)) * (K >> 5) + (k0 >> 5)) * 1024
             + (size_t)(((ng & 15) | (k8 << 4)) << 4);
  *(uint4*)(hi + off) = pack8(hs);
  *(uint4*)(lo + off) = pack8(ls);
}

// ---------------------------------------------------------------------------
// Split-bf16 MFMA GEMM, path-batched over z.
// z < zsplit -> path A (WplA, biasA, codeA), else path B.
// A planes: hi = Apl + z*sA, lo = hi + K*4096 (M=2048 rows per z).
// MODE 0: C=acc+bias  1: +residF(fp32, shared)  2: gelu->planes  3: +resid planes
// ---------------------------------------------------------------------------
template<int MT, int MODE>
__global__ __launch_bounds__(256)
void gemm_fb(const char* __restrict__ Apl, long sA,
             const char* __restrict__ WplA, const char* __restrict__ WplB,
             int zsplit, long sW,
             const float* __restrict__ biasA, const float* __restrict__ biasB,
             long sBias,
             const float* __restrict__ residF,
             const char* __restrict__ Rpl, long sR,
             float* __restrict__ C, long sC,
             char* __restrict__ Ppl, long sP,
             int N, int K,
             const float* __restrict__ sel, int codeA, int codeB)
{
  constexpr int TILE = MT * 32;
  constexpr int NB = 2 * MT;                   // 1KB blocks per plane
  __shared__ __align__(16) char lds[TILE * 256];  // Ahi|Alo|Bhi|Blo
  const int arow0 = blockIdx.y * TILE, bcol0 = blockIdx.x * TILE;
  const int z = blockIdx.z;
  const bool isA = (z < zsplit);
  const int code = isA ? codeA : codeB;
  if (code && sel[arow0 >> 8] != (float)code) return;
  const int zi = isA ? z : z - zsplit;
  const char* Ahi = Apl + (size_t)z * sA;
  const char* Alo = Ahi + (size_t)K * 4096;
  const char* whi = (isA ? WplA : WplB) + (size_t)zi * sW;
  const char* wlo = whi + (size_t)K * N * 2;
  const float* bz = (isA ? biasA : biasB) + (size_t)zi * sBias;
  const int tid = threadIdx.x, lane = tid & 63, wv = tid >> 6;
  const int wm = wv >> 1, wn = wv & 1;
  const int KC = K >> 5;
  const char* bases[4] = {Ahi, Alo, whi, wlo};
  const char* wbase = bases[wv];
  const int rt0 = ((wv < 2) ? arow0 : bcol0) >> 4;
  float4v acc[MT][MT];
  #pragma unroll
  for (int i = 0; i < MT; ++i)
    #pragma unroll
    for (int j = 0; j < MT; ++j)
      acc[i][j] = (float4v){0.f, 0.f, 0.f, 0.f};

  for (int kc = 0; kc < KC; ++kc) {
    #pragma unroll
    for (int j = 0; j < NB; ++j) {
      size_t g = ((((size_t)(rt0 + j)) * KC + kc) << 10) + (size_t)lane * 16;
      dma16(wbase + g, lds + (wv * NB + j) * 1024);
    }
    __syncthreads();
    short8 bh[MT], bl[MT];
    #pragma unroll
    for (int nt = 0; nt < MT; ++nt) {
      bh[nt] = *(const short8*)(lds + (4 * MT + wn * MT + nt) * 1024 + lane * 16);
      bl[nt] = *(const short8*)(lds + (6 * MT + wn * MT + nt) * 1024 + lane * 16);
    }
    #pragma unroll
    for (int mt = 0; mt < MT; ++mt) {
      short8 ah = *(const short8*)(lds + (wm * MT + mt) * 1024 + lane * 16);
      short8 al = *(const short8*)(lds + (2 * MT + wm * MT + mt) * 1024 + lane * 16);
      #pragma unroll
      for (int nt = 0; nt < MT; ++nt) {
        acc[mt][nt] = __builtin_amdgcn_mfma_f32_16x16x32_bf16(ah, bh[nt], acc[mt][nt], 0, 0, 0);
        acc[mt][nt] = __builtin_amdgcn_mfma_f32_16x16x32_bf16(ah, bl[nt], acc[mt][nt], 0, 0, 0);
        acc[mt][nt] = __builtin_amdgcn_mfma_f32_16x16x32_bf16(al, bh[nt], acc[mt][nt], 0, 0, 0);
      }
    }
    __syncthreads();
  }
  // epilogue: C layout col=lane&15, row=quad*4+reg
  const int qd = lane >> 4, cI = lane & 15;
  const int KCo = N >> 5;
  float* Cz = (MODE == 2) ? nullptr : (C + (size_t)z * sC);
  const char* Rhi = (MODE == 3) ? (Rpl + (size_t)z * sR) : nullptr;
  const char* Rlo = (MODE == 3) ? (Rhi + (size_t)N * 4096) : nullptr;
  char* Phi = (MODE == 2) ? (Ppl + (size_t)z * sP) : nullptr;
  char* Plo = (MODE == 2) ? (Phi + (size_t)N * 4096) : nullptr;
  #pragma unroll
  for (int mt = 0; mt < MT; ++mt) {
    #pragma unroll
    for (int nt = 0; nt < MT; ++nt) {
      int row0 = arow0 + (wm * MT + mt) * 16 + qd * 4;
      int col  = bcol0 + (wn * MT + nt) * 16 + cI;
      float bv = bz[col];
      #pragma unroll
      for (int r = 0; r < 4; ++r) {
        int row = row0 + r;
        float v = acc[mt][nt][r] + bv;
        if (MODE == 1) v += residF[(size_t)row * N + col];
        if (MODE == 3) {
          size_t ra = fbaddr(row, col, KCo);
          v += bf2f(*(const unsigned short*)(Rhi + ra))
             + bf2f(*(const unsigned short*)(Rlo + ra));
        }
        if (MODE == 2) {
          v = 0.5f * v * (1.0f + erff(v * 0.70710678118654752f));
          unsigned short hb = f2bf(v);
          unsigned short lb = f2bf(v - bf2f(hb));
          size_t pa = fbaddr(row, col, KCo);
          *(unsigned short*)(Phi + pa) = hb;
          *(unsigned short*)(Plo + pa) = lb;
        } else {
          Cz[(size_t)row * N + col] = v;
        }
      }
    }
  }
}

// ---------------------------------------------------------------------------
// Attention (fp32 VALU), path-batched: z in [0, 96*paths); path = z/96.
// qkv layout: [path][3][2048][768] fp32.
// ---------------------------------------------------------------------------
__global__ __launch_bounds__(256)
void attn_scores(const float* __restrict__ qkv, const float* __restrict__ mask,
                 float* __restrict__ sc,
                 const float* __restrict__ sel, int codeA, int codeB)
{
  const int z = blockIdx.z;
  const int path = z / 96, zz = z - path * 96;
  const int b = zz / NHq, hh = zz % NHq;
  const int code = path ? codeB : codeA;
  if (code && sel[b] != (float)code) return;
  const float* q = qkv + (size_t)path * 3 * BSH;
  const float* k = q + BSH;
  const long base = (long)b * Sq * Hq + hh * 64;
  const int im = blockIdx.y, in = blockIdx.x;
  const int tid = threadIdx.x;
  const int tx = tid & 15, ty = tid >> 4;
  __shared__ __align__(16) float Qs[16][68];
  __shared__ __align__(16) float Ks[16][68];
  float acc[4][4] = {};
  const int row = tid >> 2;
  const int kl = (tid & 3) << 2;
  for (int kt = 0; kt < 64; kt += 16) {
    float4 a4 = *(const float4*)(q + base + (long)(im * 64 + row) * Hq + kt + kl);
    Qs[kl + 0][row] = a4.x; Qs[kl + 1][row] = a4.y; Qs[kl + 2][row] = a4.z; Qs[kl + 3][row] = a4.w;
    float4 b4 = *(const float4*)(k + base + (long)(in * 64 + row) * Hq + kt + kl);
    Ks[kl + 0][row] = b4.x; Ks[kl + 1][row] = b4.y; Ks[kl + 2][row] = b4.z; Ks[kl + 3][row] = b4.w;
    __syncthreads();
    #pragma unroll
    for (int kk = 0; kk < 16; ++kk) {
      float a[4], bb[4];
      *(float4*)a = *(const float4*)&Qs[kk][ty * 4];
      *(float4*)bb = *(const float4*)&Ks[kk][tx * 4];
      #pragma unroll
      for (int i2 = 0; i2 < 4; ++i2)
        #pragma unroll
        for (int j2 = 0; j2 < 4; ++j2)
          acc[i2][j2] = fmaf(a[i2], bb[j2], acc[i2][j2]);
    }
    __syncthreads();
  }
  #pragma unroll
  for (int i2 = 0; i2 < 4; ++i2) {
    int ig = im * 64 + ty * 4 + i2;
    #pragma unroll
    for (int j2 = 0; j2 < 4; ++j2) {
      int jg = in * 64 + tx * 4 + j2;
      sc[(long)z * (Sq * Sq) + (long)ig * Sq + jg] = acc[i2][j2] * 0.125f + mask[b * Sq + jg];
    }
  }
}

__global__ __launch_bounds__(256)
void softmax256(float* __restrict__ sc, const float* __restrict__ sel,
                int codeA, int codeB)
{
  const int wid = threadIdx.x >> 6, lane = threadIdx.x & 63;
  const long row = (long)blockIdx.x * 4 + wid;
  const int z = (int)(row >> 8);
  const int path = z / 96, zz = z - path * 96;
  const int code = path ? codeB : codeA;
  if (code && sel[zz / NHq] != (float)code) return;
  float* p = sc + row * Sq;
  float v[4];
  float m = -1e30f;
  #pragma unroll
  for (int t = 0; t < 4; ++t) { v[t] = p[lane + t * 64]; m = fmaxf(m, v[t]); }
  #pragma unroll
  for (int off = 32; off >= 1; off >>= 1) m = fmaxf(m, __shfl_xor(m, off));
  float s = 0.0f;
  #pragma unroll
  for (int t = 0; t < 4; ++t) { v[t] = expf(v[t] - m); s += v[t]; }
  #pragma unroll
  for (int off = 32; off >= 1; off >>= 1) s += __shfl_xor(s, off);
  #pragma unroll
  for (int t = 0; t < 4; ++t) p[lane + t * 64] = v[t] / s;
}

// ctx -> FB16 planes; out per path at ctxpl + path*PLPAIR
__global__ __launch_bounds__(256)
void attn_ctx(const float* __restrict__ sc, const float* __restrict__ qkv,
              char* __restrict__ ctxpl,
              const float* __restrict__ sel, int codeA, int codeB)
{
  const int z = blockIdx.z;
  const int path = z / 96, zz = z - path * 96;
  const int b = zz / NHq, hh = zz % NHq;
  const int code = path ? codeB : codeA;
  if (code && sel[b] != (float)code) return;
  const float* P = sc + (long)z * (Sq * Sq);
  const float* V = qkv + (size_t)path * 3 * BSH + 2 * BSH + (long)b * Sq * Hq + hh * 64;
  char* Phi = ctxpl + (size_t)path * PLPAIR;
  char* Plo = Phi + PLH;
  const int im = blockIdx.y;
  const int tid = threadIdx.x;
  const int tx = tid & 15, ty = tid >> 4;
  __shared__ __align__(16) float Ps[16][68];
  __shared__ __align__(16) float Vs[16][64];
  float acc[4][4] = {};
  const int row = tid >> 2;
  const int kl = (tid & 3) << 2;
  const int vr = tid >> 4, vc = (tid & 15) << 2;
  for (int kt = 0; kt < Sq; kt += 16) {
    float4 a4 = *(const float4*)(P + (long)(im * 64 + row) * Sq + kt + kl);
    Ps[kl + 0][row] = a4.x; Ps[kl + 1][row] = a4.y; Ps[kl + 2][row] = a4.z; Ps[kl + 3][row] = a4.w;
    *(float4*)&Vs[vr][vc] = *(const float4*)(V + (long)(kt + vr) * Hq + vc);
    __syncthreads();
    #pragma unroll
    for (int kk = 0; kk < 16; ++kk) {
      float a[4], bb[4];
      *(float4*)a = *(const float4*)&Ps[kk][ty * 4];
      *(float4*)bb = *(const float4*)&Vs[kk][tx * 4];
      #pragma unroll
      for (int i2 = 0; i2 < 4; ++i2)
        #pragma unroll
        for (int j2 = 0; j2 < 4; ++j2)
          acc[i2][j2] = fmaf(a[i2], bb[j2], acc[i2][j2]);
    }
    __syncthreads();
  }
  const int c0 = hh * 64 + tx * 4;
  #pragma unroll
  for (int i2 = 0; i2 < 4; ++i2) {
    int grow = b * 256 + im * 64 + ty * 4 + i2;
    unsigned short h[4], l[4];
    #pragma unroll
    for (int j2 = 0; j2 < 4; ++j2) {
      float x = acc[i2][j2];
      h[j2] = f2bf(x);
      l[j2] = f2bf(x - bf2f(h[j2]));
    }
    size_t pa = fbaddr(grow, c0, 24);
    uint2 uh; uh.x = (unsigned)h[0] | ((unsigned)h[1] << 16); uh.y = (unsigned)h[2] | ((unsigned)h[3] << 16);
    uint2 ul; ul.x = (unsigned)l[0] | ((unsigned)l[1] << 16); ul.y = (unsigned)l[2] | ((unsigned)l[3] << 16);
    *(uint2*)(Phi + pa) = uh;
    *(uint2*)(Plo + pa) = ul;
  }
}

// ---------------------------------------------------------------------------
// LayerNorm (row of 768) -> FB16 planes, path-batched.
// x contiguous [paths][2048][768] fp32; out planes ypl + path*PLPAIR.
// ---------------------------------------------------------------------------
__global__ __launch_bounds__(256)
void ln2(const float* __restrict__ x, char* __restrict__ ypl,
         const float* __restrict__ gA, const float* __restrict__ bA,
         const float* __restrict__ gB, const float* __restrict__ bB,
         const float* __restrict__ sel, int codeA, int codeB)
{
  const int row = blockIdx.x, t = threadIdx.x;
  const int path = row >> 11;
  const int lrow = row & 2047;
  const int code = path ? codeB : codeA;
  if (code && sel[lrow >> 8] != (float)code) return;
  const float* g = path ? gB : gA;
  const float* bta = path ? bB : bA;
  const float* xr = x + (size_t)row * Hq;
  __shared__ float xs[Hq];
  __shared__ float ss[4], qq[4];
  float a = xr[t], b = xr[t + 256], c = xr[t + 512];
  xs[t] = a; xs[t + 256] = b; xs[t + 512] = c;
  float s = a + b + c;
  float q2 = a * a + b * b + c * c;
  #pragma unroll
  for (int off = 32; off >= 1; off >>= 1) { s += __shfl_xor(s, off); q2 += __shfl_xor(q2, off); }
  const int wid = t >> 6, lane = t & 63;
  if (lane == 0) { ss[wid] = s; qq[wid] = q2; }
  __syncthreads();
  s = ss[0] + ss[1] + ss[2] + ss[3];
  q2 = qq[0] + qq[1] + qq[2] + qq[3];
  const float mean = s * (1.0f / 768.0f);
  const float var = q2 * (1.0f / 768.0f) - mean * mean;
  const float r = rsqrtf(var + 1e-12f);
  if (t < 96) {
    const int c0 = t * 8;
    unsigned short hs[8], ls[8];
    #pragma unroll
    for (int j = 0; j < 8; ++j) {
      float y = (xs[c0 + j] - mean) * r * g[c0 + j] + bta[c0 + j];
      hs[j] = f2bf(y);
      ls[j] = f2bf(y - bf2f(hs[j]));
    }
    char* yh = ypl + (size_t)path * PLPAIR;
    char* yl = yh + PLH;
    size_t pa = fbaddr(lrow, c0, 24);
    *(uint4*)(yh + pa) = pack8(hs);
    *(uint4*)(yl + pa) = pack8(ls);
  }
}

// ---------------------------------------------------------------------------
// h0: copy fp32 + emit planes. grid 768 x 256.
// ---------------------------------------------------------------------------
__global__ __launch_bounds__(256)
void h0split(const float* __restrict__ src, float* __restrict__ hout,
             char* __restrict__ hh, char* __restrict__ hl)
{
  const int idx = blockIdx.x * 256 + threadIdx.x;
  const int row = idx / 96, c0 = (idx % 96) * 8;
  const float* p = src + (size_t)row * Hq + c0;
  float v[8];
  *(float4*)&v[0] = ((const float4*)p)[0];
  *(float4*)&v[4] = ((const float4*)p)[1];
  float* o = hout + (size_t)row * Hq + c0;
  ((float4*)o)[0] = *(float4*)&v[0];
  ((float4*)o)[1] = *(float4*)&v[4];
  unsigned short hs[8], ls[8];
  #pragma unroll
  for (int j = 0; j < 8; ++j) { hs[j] = f2bf(v[j]); ls[j] = f2bf(v[j] - bf2f(hs[j])); }
  size_t pa = fbaddr(row, c0, 24);
  *(uint4*)(hh + pa) = pack8(hs);
  *(uint4*)(hl + pa) = pack8(ls);
}

// ---------------------------------------------------------------------------
// Select: h = (code==1)?base:(code==2)?large:h ; refresh fp32 + planes
// ---------------------------------------------------------------------------
__global__ __launch_bounds__(256)
void select_fb(float* __restrict__ hout, char* __restrict__ hh, char* __restrict__ hl,
               const char* __restrict__ bh, const char* __restrict__ bl,
               const char* __restrict__ gh, const char* __restrict__ gl,
               const float* __restrict__ sel)
{
  const int idx = blockIdx.x * 256 + threadIdx.x;
  const int row = idx / 96, c0 = (idx % 96) * 8;
  const int b = row >> 8;
  const float code = sel[b];
  const size_t pa = fbaddr(row, c0, 24);
  float v[8];
  if (code == 1.0f || code == 2.0f) {
    const char* sh = (code == 1.0f) ? bh : gh;
    const char* sl = (code == 1.0f) ? bl : gl;
    uint4 H = *(const uint4*)(sh + pa);
    uint4 L = *(const uint4*)(sl + pa);
    const unsigned* hw = (const unsigned*)&H;
    const unsigned* lw = (const unsigned*)&L;
    #pragma unroll
    for (int j = 0; j < 8; ++j) {
      unsigned short hb = (unsigned short)(hw[j >> 1] >> ((j & 1) * 16));
      unsigned short lb = (unsigned short)(lw[j >> 1] >> ((j & 1) * 16));
      v[j] = bf2f(hb) + bf2f(lb);
    }
  } else {
    const float* p = hout + (size_t)row * Hq + c0;
    *(float4*)&v[0] = ((const float4*)p)[0];
    *(float4*)&v[4] = ((const float4*)p)[1];
  }
  float* o = hout + (size_t)row * Hq + c0;
  ((float4*)o)[0] = *(float4*)&v[0];
  ((float4*)o)[1] = *(float4*)&v[4];
  unsigned short hs[8], ls[8];
  #pragma unroll
  for (int j = 0; j < 8; ++j) { hs[j] = f2bf(v[j]); ls[j] = f2bf(v[j] - bf2f(hs[j])); }
  *(uint4*)(hh + pa) = pack8(hs);
  *(uint4*)(hl + pa) = pack8(ls);
}

// ---------------------------------------------------------------------------
// Router — inactive-sample early-out
// ---------------------------------------------------------------------------
__global__ __launch_bounds__(256)
void router_kernel(const float* __restrict__ h,
                   const float* __restrict__ A_pw, const float* __restrict__ A_pb,
                   const float* __restrict__ A_cw, const float* __restrict__ A_cb,
                   const float* __restrict__ E_pw, const float* __restrict__ E_pb,
                   const float* __restrict__ E_cw, const float* __restrict__ E_cb,
                   float* __restrict__ active,
                   float* __restrict__ probs_out, float* __restrict__ acts_out,
                   float* __restrict__ exit_logits, float* __restrict__ exit_part,
                   float* __restrict__ sel_code, int part)
{
  const int b = blockIdx.x, t = threadIdx.x;
  const bool act = (active[b] != 0.0f);
  if (!act) {
    if (t == 0) {
      probs_out[b * 3 + 0] = 1.0f;
      probs_out[b * 3 + 1] = 1.0f;
      probs_out[b * 3 + 2] = 1.0f;
      acts_out[b] = 0.0f;
      sel_code[b] = 0.0f;
    }
    return;
  }
  __shared__ float hrow[Hq], pooled[Hq];
  __shared__ float red[3][256];
  __shared__ float resL[3];
  for (int c = t; c < Hq; c += 256) hrow[c] = h[(long)b * Sq * Hq + c];
  __syncthreads();
  for (int c = t; c < Hq; c += 256) {
    float s = A_pb[c];
    for (int r = 0; r < Hq; ++r) s = fmaf(hrow[r], A_pw[(long)r * Hq + c], s);
    pooled[c] = tanhf(s);
  }
  __syncthreads();
  {
    float p0 = 0, p1 = 0, p2 = 0;
    for (int r = t; r < Hq; r += 256) {
      float p = pooled[r];
      p0 = fmaf(p, A_cw[r * 3 + 0], p0);
      p1 = fmaf(p, A_cw[r * 3 + 1], p1);
      p2 = fmaf(p, A_cw[r * 3 + 2], p2);
    }
    red[0][t] = p0; red[1][t] = p1; red[2][t] = p2;
  }
  __syncthreads();
  for (int s2 = 128; s2 > 0; s2 >>= 1) {
    if (t < s2) { red[0][t] += red[0][t + s2]; red[1][t] += red[1][t + s2]; red[2][t] += red[2][t + s2]; }
    __syncthreads();
  }
  if (t == 0) { resL[0] = red[0][0] + A_cb[0]; resL[1] = red[1][0] + A_cb[1]; resL[2] = red[2][0] + A_cb[2]; }
  __syncthreads();
  for (int c = t; c < Hq; c += 256) {
    float s = E_pb[c];
    for (int r = 0; r < Hq; ++r) s = fmaf(hrow[r], E_pw[(long)r * Hq + c], s);
    pooled[c] = tanhf(s);
  }
  __syncthreads();
  {
    float p0 = 0, p1 = 0;
    for (int r = t; r < Hq; r += 256) {
      float p = pooled[r];
      p0 = fmaf(p, E_cw[r * 2 + 0], p0);
      p1 = fmaf(p, E_cw[r * 2 + 1], p1);
    }
    red[0][t] = p0; red[1][t] = p1;
  }
  __syncthreads();
  for (int s2 = 128; s2 > 0; s2 >>= 1) {
    if (t < s2) { red[0][t] += red[0][t + s2]; red[1][t] += red[1][t + s2]; }
    __syncthreads();
  }
  if (t == 0) {
    const float e0 = red[0][0] + E_cb[0], e1 = red[1][0] + E_cb[1];
    const float l0 = resL[0], l1 = resL[1], l2 = resL[2];
    int action = 0; float bv = l0;
    if (l1 > bv) { bv = l1; action = 1; }
    if (l2 > bv) { bv = l2; action = 2; }
    const float x0 = expf(l0 - bv), x1 = expf(l1 - bv), x2 = expf(l2 - bv);
    const float ssum = x0 + x1 + x2;
    probs_out[b * 3 + 0] = x0 / ssum;
    probs_out[b * 3 + 1] = x1 / ssum;
    probs_out[b * 3 + 2] = x2 / ssum;
    acts_out[b] = (float)action;
    if (action == 0) {
      exit_logits[b * 2 + 0] = e0;
      exit_logits[b * 2 + 1] = e1;
      exit_part[b] = (float)part;
    }
    sel_code[b] = (float)action;
    active[b] = (action != 0) ? 1.0f : 0.0f;
  }
}

__global__ __launch_bounds__(64)
void init_kernel(float* __restrict__ active, float* __restrict__ exit_logits,
                 float* __restrict__ exit_part)
{
  const int t = threadIdx.x;
  if (t < 8) { active[t] = 1.0f; exit_part[t] = -1.0f; }
  if (t < 16) exit_logits[t] = 0.0f;
}

// ---------------------------------------------------------------------------
extern "C" void kernel_launch(void* const* d_in, const int* in_sizes, int n_in,
                              void* d_out, int out_size, void* d_ws, size_t ws_size,
                              hipStream_t stream)
{
  (void)in_sizes; (void)n_in; (void)out_size;
  const float* hidden   = (const float*)d_in[0];
  const float* mask     = (const float*)d_in[1];
  const float* L_attn_w = (const float*)d_in[2];
  const float* L_attn_b = (const float*)d_in[3];
  const float* L_ln_g   = (const float*)d_in[4];
  const float* L_ln_b   = (const float*)d_in[5];
  const float* L_wi     = (const float*)d_in[6];
  const float* L_bi     = (const float*)d_in[7];
  const float* L_wo     = (const float*)d_in[8];
  const float* L_bo     = (const float*)d_in[9];
  const float* S_attn_w = (const float*)d_in[10];
  const float* S_attn_b = (const float*)d_in[11];
  const float* S_ln_g   = (const float*)d_in[12];
  const float* S_ln_b   = (const float*)d_in[13];
  const float* S_wi     = (const float*)d_in[14];
  const float* S_bi     = (const float*)d_in[15];
  const float* S_wo     = (const float*)d_in[16];
  const float* S_bo     = (const float*)d_in[17];
  const float* E_pw     = (const float*)d_in[18];
  const float* E_pb     = (const float*)d_in[19];
  const float* E_cw     = (const float*)d_in[20];
  const float* E_cb     = (const float*)d_in[21];
  const float* A_pw     = (const float*)d_in[22];
  const float* A_pb     = (const float*)d_in[23];
  const float* A_cw     = (const float*)d_in[24];
  const float* A_cb     = (const float*)d_in[25];

  float* out = (float*)d_out;
  float* h      = out;
  float* active = out + 1572864;
  float* probs  = out + 1572872;
  float* acts   = out + 1573016;
  float* exitl  = out + 1573064;
  float* exitp  = out + 1573080;

  char* ws = (char*)d_ws;
  float* sel    = (float*)ws;
  char* hpl     = ws + 256;
  char* basepl  = hpl + PLPAIR;
  char* j0pl    = basepl + PLPAIR;          // contiguous after basepl (LN2 s1)
  char* largepl = j0pl + PLPAIR;
  char* ctxpl   = largepl + PLPAIR;
  char* qkvreg  = ctxpl + 2 * PLPAIR;       // 37,748,736 B (6 fp32 slots)
  char* big     = qkvreg + 37748736L;       // 50,331,648 B
  char* warena  = big + 50331648L;
  const size_t actBytes = (size_t)(warena - ws);
  const bool full = ws_size >= actBytes + 18ULL * SLOTW;

  // overlays
  float* qkv    = (float*)qkvreg;
  char*  x1pl   = qkvreg;                   // after qkv q/k dead (post-ctx)
  float* t2     = (float*)(qkvreg + 2 * PLPAIR);
  float* scores = (float*)big;
  float* Oout   = (float*)big;              // after scores dead (post-ctx)
  char*  ffnpl  = big;                      // after Oout dead (post-LN1)

  // weight arena regions (JIT fallback)
  char* R1a = warena;
  char* R1b = warena + 9437184L;
  char* R2a = warena + 18874368L;
  char* R2b = warena + 28311552L;

  init_kernel<<<dim3(1), 64, 0, stream>>>(active, exitl, exitp);
  h0split<<<dim3(768), 256, 0, stream>>>(hidden, h, hpl, hpl + PLH);

  if (full) {
    // Convert ALL weights once: slots 0..11 = L layers, 12..17 = S layers.
    prep_w<<<dim3(12, 24, 48), 256, 0, stream>>>(L_attn_w, warena,
        768, 768, 589824L, 2359296L, 4, MATATTN, SLOTW, sel, 0);
    prep_w<<<dim3(12, 24, 24), 256, 0, stream>>>(S_attn_w, warena + 12 * SLOTW,
        768, 768, 589824L, 2359296L, 4, MATATTN, SLOTW, sel, 0);
    prep_w<<<dim3(48, 24, 12), 256, 0, stream>>>(L_wi, warena + WIOFF,
        768, 3072, 0L, 2359296L, 1, 0L, SLOTW, sel, 0);
    prep_w<<<dim3(48, 24, 6), 256, 0, stream>>>(S_wi, warena + 12 * SLOTW + WIOFF,
        768, 3072, 0L, 2359296L, 1, 0L, SLOTW, sel, 0);
    prep_w<<<dim3(12, 96, 12), 256, 0, stream>>>(L_wo, warena + WOOFF,
        3072, 768, 0L, 2359296L, 1, 0L, SLOTW, sel, 0);
    prep_w<<<dim3(12, 96, 6), 256, 0, stream>>>(S_wo, warena + 12 * SLOTW + WOOFF,
        3072, 768, 0L, 2359296L, 1, 0L, SLOTW, sel, 0);
  }

  for (int i = 0; i < 6; ++i) {
    const int j0 = 2 * i, j1 = 2 * i + 1;
    // weight plane pointers per tier
    const char *attnA, *attnB, *wiA, *wiB, *woA, *woB, *attnJ1, *wiJ1, *woJ1;
    if (full) {
      const char* sS  = warena + (12 + i) * SLOTW;
      const char* sL0 = warena + (size_t)j0 * SLOTW;
      const char* sL1 = warena + (size_t)j1 * SLOTW;
      attnA = sS;  wiA = sS + WIOFF;  woA = sS + WOOFF;
      attnB = sL0; wiB = sL0 + WIOFF; woB = sL0 + WOOFF;
      attnJ1 = sL1; wiJ1 = sL1 + WIOFF; woJ1 = sL1 + WOOFF;
    } else {
      attnA = R1a; attnB = R1b; wiA = R2a; wiB = R2b;
      woA = R1a; woB = R1b; attnJ1 = R2a; wiJ1 = R1a; woJ1 = R1b;
    }
    // biases / LN params
    const float* qkvBA = S_attn_b + (long)i * 4 * Hq;
    const float* qkvBB = L_attn_b + (long)j0 * 4 * Hq;
    const float* oBA   = qkvBA + 3 * Hq;
    const float* oBB   = qkvBB + 3 * Hq;
    const float* biA   = S_bi + (long)i * FFq;
    const float* biB   = L_bi + (long)j0 * FFq;
    const float* boA   = S_bo + (long)i * Hq;
    const float* boB   = L_bo + (long)j0 * Hq;
    const float* lgA   = S_ln_g + (long)i * 2 * Hq;
    const float* lbA   = S_ln_b + (long)i * 2 * Hq;
    const float* lgB   = L_ln_g + (long)j0 * 2 * Hq;
    const float* lbB   = L_ln_b + (long)j0 * 2 * Hq;
    const float* qkvB1 = L_attn_b + (long)j1 * 4 * Hq;
    const float* oB1   = qkvB1 + 3 * Hq;
    const float* bi1   = L_bi + (long)j1 * FFq;
    const float* bo1   = L_bo + (long)j1 * Hq;
    const float* lg1   = L_ln_g + (long)j1 * 2 * Hq;
    const float* lb1   = L_ln_b + (long)j1 * 2 * Hq;

    router_kernel<<<dim3(Bq), 256, 0, stream>>>(
        h, A_pw, A_pb, A_cw, A_cb,
        E_pw + (long)i * Hq * Hq, E_pb + i * Hq,
        E_cw + (long)i * Hq * 2, E_cb + i * 2,
        active, probs + i * 24, acts + i * 8, exitl, exitp, sel, i);

    if (!full) {
      prep_w<<<dim3(12, 24, 4), 256, 0, stream>>>(S_attn_w + (long)i * 4 * Hq * Hq, R1a,
          768, 768, 589824L, 0L, 4, MATATTN, 0L, sel, 1);
      prep_w<<<dim3(12, 24, 4), 256, 0, stream>>>(L_attn_w + (long)j0 * 4 * Hq * Hq, R1b,
          768, 768, 589824L, 0L, 4, MATATTN, 0L, sel, 2);
      prep_w<<<dim3(48, 24, 1), 256, 0, stream>>>(S_wi + (long)i * Hq * FFq, R2a,
          768, 3072, 0L, 0L, 1, 0L, 0L, sel, 1);
      prep_w<<<dim3(48, 24, 1), 256, 0, stream>>>(L_wi + (long)j0 * Hq * FFq, R2b,
          768, 3072, 0L, 0L, 1, 0L, 0L, sel, 2);
    }

    // ---------------- stage 1: base (path A, code 1) + large j0 (path B, code 2)
    gemm_fb<2, 0><<<dim3(12, 32, 6), 256, 0, stream>>>(
        hpl, 0L, attnA, attnB, 3, MATATTN, qkvBA, qkvBB, (long)Hq,
        nullptr, nullptr, 0L, qkv, (long)BSH, nullptr, 0L,
        768, 768, sel, 1, 2);
    attn_scores<<<dim3(4, 4, 192), 256, 0, stream>>>(qkv, mask, scores, sel, 1, 2);
    softmax256<<<dim3(192 * 64), 256, 0, stream>>>(scores, sel, 1, 2);
    attn_ctx<<<dim3(1, 4, 192), 256, 0, stream>>>(scores, qkv, ctxpl, sel, 1, 2);
    gemm_fb<2, 1><<<dim3(12, 32, 2), 256, 0, stream>>>(
        ctxpl, PLPAIR, attnA + 3 * MATATTN, attnB + 3 * MATATTN, 1, 0L,
        oBA, oBB, 0L, h, nullptr, 0L, Oout, (long)BSH, nullptr, 0L,
        768, 768, sel, 1, 2);
    if (!full) {
      prep_w<<<dim3(12, 96, 1), 256, 0, stream>>>(S_wo + (long)i * FFq * Hq, R1a,
          3072, 768, 0L, 0L, 1, 0L, 0L, sel, 1);
      prep_w<<<dim3(12, 96, 1), 256, 0, stream>>>(L_wo + (long)j0 * FFq * Hq, R1b,
          3072, 768, 0L, 0L, 1, 0L, 0L, sel, 2);
    }
    ln2<<<dim3(4096), 256, 0, stream>>>(Oout, x1pl, lgA, lbA, lgB, lbB, sel, 1, 2);
    gemm_fb<4, 2><<<dim3(24, 16, 2), 256, 0, stream>>>(
        x1pl, PLPAIR, wiA, wiB, 1, 0L, biA, biB, 0L,
        nullptr, nullptr, 0L, nullptr, 0L, ffnpl, 25165824L,
        3072, 768, sel, 1, 2);
    if (!full)
      prep_w<<<dim3(12, 24, 4), 256, 0, stream>>>(L_attn_w + (long)j1 * 4 * Hq * Hq, R2a,
          768, 768, 589824L, 0L, 4, MATATTN, 0L, sel, 2);
    gemm_fb<2, 3><<<dim3(12, 32, 2), 256, 0, stream>>>(
        ffnpl, 25165824L, woA, woB, 1, 0L, boA, boB, 0L,
        nullptr, x1pl, PLPAIR, t2, (long)BSH, nullptr, 0L,
        768, 3072, sel, 1, 2);
    if (!full) {
      prep_w<<<dim3(48, 24, 1), 256, 0, stream>>>(L_wi + (long)j1 * Hq * FFq, R1a,
          768, 3072, 0L, 0L, 1, 0L, 0L, sel, 2);
      prep_w<<<dim3(12, 96, 1), 256, 0, stream>>>(L_wo + (long)j1 * FFq * Hq, R1b,
          3072, 768, 0L, 0L, 1, 0L, 0L, sel, 2);
    }
    ln2<<<dim3(4096), 256, 0, stream>>>(t2, basepl, lgA + Hq, lbA + Hq,
                                        lgB + Hq, lbB + Hq, sel, 1, 2);

    // ---------------- stage 2: large j1 (single path, code 2), input j0pl
    gemm_fb<2, 0><<<dim3(12, 32, 3), 256, 0, stream>>>(
        j0pl, 0L, attnJ1, attnJ1, 3, MATATTN, qkvB1, qkvB1, (long)Hq,
        nullptr, nullptr, 0L, qkv, (long)BSH, nullptr, 0L,
        768, 768, sel, 2, 2);
    attn_scores<<<dim3(4, 4, 96), 256, 0, stream>>>(qkv, mask, scores, sel, 2, 2);
    softmax256<<<dim3(96 * 64), 256, 0, stream>>>(scores, sel, 2, 2);
    attn_ctx<<<dim3(1, 4, 96), 256, 0, stream>>>(scores, qkv, ctxpl, sel, 2, 2);
    gemm_fb<2, 3><<<dim3(12, 32, 1), 256, 0, stream>>>(
        ctxpl, PLPAIR, attnJ1 + 3 * MATATTN, attnJ1 + 3 * MATATTN, 1, 0L,
        oB1, oB1, 0L, nullptr, j0pl, 0L, Oout, (long)BSH, nullptr, 0L,
        768, 768, sel, 2, 2);
    ln2<<<dim3(2048), 256, 0, stream>>>(Oout, x1pl, lg1, lb1, lg1, lb1, sel, 2, 2);
    gemm_fb<4, 2><<<dim3(24, 16, 1), 256, 0, stream>>>(
        x1pl, PLPAIR, wiJ1, wiJ1, 1, 0L, bi1, bi1, 0L,
        nullptr, nullptr, 0L, nullptr, 0L, ffnpl, 25165824L,
        3072, 768, sel, 2, 2);
    gemm_fb<2, 3><<<dim3(12, 32, 1), 256, 0, stream>>>(
        ffnpl, 25165824L, woJ1, woJ1, 1, 0L, bo1, bo1, 0L,
        nullptr, x1pl, PLPAIR, t2, (long)BSH, nullptr, 0L,
        768, 3072, sel, 2, 2);
    ln2<<<dim3(2048), 256, 0, stream>>>(t2, largepl, lg1 + Hq, lb1 + Hq,
                                        lg1 + Hq, lb1 + Hq, sel, 2, 2);

    select_fb<<<dim3(768), 256, 0, stream>>>(h, hpl, hpl + PLH,
                                             basepl, basepl + PLH,
                                             largepl, largepl + PLH, sel);
  }
}

// Round 3
// 3477.906 us; speedup vs baseline: 1.6381x; 1.1599x over previous
//
#include <hip/hip_runtime.h>
#include <math.h>

#define Bq 8
#define Sq 256
#define Hq 768
#define FFq 3072
#define NHq 12
#define MROWS (Bq*Sq)          /* 2048 */
#define BSH (Bq*Sq*Hq)         /* 1,572,864 floats */

#define MATATTN 2359296L       /* bytes: one 768x768 plane pair (hi+lo) */
#define PLH     3145728L       /* bytes: one 2048x768 bf16 plane (hi or lo) */
#define PLPAIR  6291456L       /* hi+lo pair for a 2048x768 activation */
#define SLOTW   28311552L      /* per-layer weight planes: attn(4)+wi+wo */
#define WIOFF   9437184L
#define WOOFF   18874368L

typedef __attribute__((ext_vector_type(8))) short short8;
typedef __attribute__((ext_vector_type(4))) float float4v;

// ---------------------------------------------------------------------------
// bf16 split helpers
// ---------------------------------------------------------------------------
__device__ __forceinline__ unsigned short f2bf(float f) {
  unsigned u = __float_as_uint(f);
  return (unsigned short)((u + 0x7fffu + ((u >> 16) & 1u)) >> 16);
}
__device__ __forceinline__ float bf2f(unsigned short h) {
  return __uint_as_float(((unsigned)h) << 16);
}
__device__ __forceinline__ uint4 pack8(const unsigned short* s) {
  uint4 u;
  u.x = (unsigned)s[0] | ((unsigned)s[1] << 16);
  u.y = (unsigned)s[2] | ((unsigned)s[3] << 16);
  u.z = (unsigned)s[4] | ((unsigned)s[5] << 16);
  u.w = (unsigned)s[6] | ((unsigned)s[7] << 16);
  return u;
}

// Fragment-blocked bf16 plane addressing (rows R, inner dim K). 1KB block per
// (rowtile=row/16, kc=k/32); lane = (row&15)|quad<<4 holds 16B = 8 bf16.
__device__ __forceinline__ size_t fbaddr(int row, int col, int KC) {
  return ((((size_t)(row >> 4)) * KC + (col >> 5)) << 10)
       + ((size_t)(((row & 15) | (((col >> 3) & 3) << 4))) << 4)
       + (size_t)((col & 7) << 1);
}

__device__ __forceinline__ void dma16(const void* g, void* l) {
  __builtin_amdgcn_global_load_lds(
      (const __attribute__((address_space(1))) unsigned int*)g,
      (__attribute__((address_space(3))) unsigned int*)l, 16, 0, 0);
}

__device__ __forceinline__ bool any_sel(const float* sel, int code) {
  bool need = false;
  #pragma unroll
  for (int i = 0; i < Bq; ++i) need |= (sel[i] == (float)code);
  return need;
}

// ---------------------------------------------------------------------------
// Weight prep: W fp32 [K][N] -> FB16 planes (rows=N, inner=K).
// z maps to (group, mat): in = Wg + gq*sInGroup + mq*sInMat (elements),
// out = planes + gq*sOutGroup + mq*sOutMat (bytes). grid (N/64, K/32, z).
// ---------------------------------------------------------------------------
__global__ __launch_bounds__(256)
void prep_w(const float* __restrict__ Wg, char* __restrict__ planes,
            int K, int N, long sInMat, long sInGroup, int zPerGroup,
            long sOutMat, long sOutGroup,
            const float* __restrict__ sel, int code)
{
  if (code && !any_sel(sel, code)) return;
  const int z = blockIdx.z;
  const int gq = z / zPerGroup, mq = z % zPerGroup;
  const float* W = Wg + (size_t)gq * sInGroup + (size_t)mq * sInMat;
  char* hi = planes + (size_t)gq * sOutGroup + (size_t)mq * sOutMat;
  char* lo = hi + (size_t)K * N * 2;
  const int n0 = blockIdx.x * 64, k0 = blockIdx.y * 32;
  const int t = threadIdx.x;
  __shared__ __align__(16) float Ws[32][68];
  {
    int rowk = t >> 3, cc = (t & 7) * 8;
    const float* src = W + (size_t)(k0 + rowk) * N + n0 + cc;
    float4 A4 = ((const float4*)src)[0];
    float4 B4 = ((const float4*)src)[1];
    *(float4*)&Ws[rowk][cc] = A4;
    *(float4*)&Ws[rowk][cc + 4] = B4;
  }
  __syncthreads();
  const int nl = (t & 15) | ((t >> 6) << 4);   // 0..63
  const int k8 = (t >> 4) & 3;
  unsigned short hs[8], ls[8];
  #pragma unroll
  for (int j = 0; j < 8; ++j) {
    float v = Ws[k8 * 8 + j][nl];
    unsigned short h = f2bf(v);
    hs[j] = h;
    ls[j] = f2bf(v - bf2f(h));
  }
  const int ng = n0 + nl;
  size_t off = (((size_t)(ng >> 4)) * (K >> 5) + (k0 >> 5)) * 1024
             + (size_t)(((ng & 15) | (k8 << 4)) << 4);
  *(uint4*)(hi + off) = pack8(hs);
  *(uint4*)(lo + off) = pack8(ls);
}

// ---------------------------------------------------------------------------
// Split-bf16 MFMA GEMM, path-batched over z.
// ---------------------------------------------------------------------------
template<int MT, int MODE>
__global__ __launch_bounds__(256)
void gemm_fb(const char* __restrict__ Apl, long sA,
             const char* __restrict__ WplA, const char* __restrict__ WplB,
             int zsplit, long sW,
             const float* __restrict__ biasA, const float* __restrict__ biasB,
             long sBias,
             const float* __restrict__ residF,
             const char* __restrict__ Rpl, long sR,
             float* __restrict__ C, long sC,
             char* __restrict__ Ppl, long sP,
             int N, int K,
             const float* __restrict__ sel, int codeA, int codeB)
{
  constexpr int TILE = MT * 32;
  constexpr int NB = 2 * MT;                   // 1KB blocks per plane
  __shared__ __align__(16) char lds[TILE * 256];  // Ahi|Alo|Bhi|Blo
  const int arow0 = blockIdx.y * TILE, bcol0 = blockIdx.x * TILE;
  const int z = blockIdx.z;
  const bool isA = (z < zsplit);
  const int code = isA ? codeA : codeB;
  if (code && sel[arow0 >> 8] != (float)code) return;
  const int zi = isA ? z : z - zsplit;
  const char* Ahi = Apl + (size_t)z * sA;
  const char* Alo = Ahi + (size_t)K * 4096;
  const char* whi = (isA ? WplA : WplB) + (size_t)zi * sW;
  const char* wlo = whi + (size_t)K * N * 2;
  const float* bz = (isA ? biasA : biasB) + (size_t)zi * sBias;
  const int tid = threadIdx.x, lane = tid & 63, wv = tid >> 6;
  const int wm = wv >> 1, wn = wv & 1;
  const int KC = K >> 5;
  const char* bases[4] = {Ahi, Alo, whi, wlo};
  const char* wbase = bases[wv];
  const int rt0 = ((wv < 2) ? arow0 : bcol0) >> 4;
  float4v acc[MT][MT];
  #pragma unroll
  for (int i = 0; i < MT; ++i)
    #pragma unroll
    for (int j = 0; j < MT; ++j)
      acc[i][j] = (float4v){0.f, 0.f, 0.f, 0.f};

  for (int kc = 0; kc < KC; ++kc) {
    #pragma unroll
    for (int j = 0; j < NB; ++j) {
      size_t g = ((((size_t)(rt0 + j)) * KC + kc) << 10) + (size_t)lane * 16;
      dma16(wbase + g, lds + (wv * NB + j) * 1024);
    }
    __syncthreads();
    short8 bh[MT], bl[MT];
    #pragma unroll
    for (int nt = 0; nt < MT; ++nt) {
      bh[nt] = *(const short8*)(lds + (4 * MT + wn * MT + nt) * 1024 + lane * 16);
      bl[nt] = *(const short8*)(lds + (6 * MT + wn * MT + nt) * 1024 + lane * 16);
    }
    #pragma unroll
    for (int mt = 0; mt < MT; ++mt) {
      short8 ah = *(const short8*)(lds + (wm * MT + mt) * 1024 + lane * 16);
      short8 al = *(const short8*)(lds + (2 * MT + wm * MT + mt) * 1024 + lane * 16);
      #pragma unroll
      for (int nt = 0; nt < MT; ++nt) {
        acc[mt][nt] = __builtin_amdgcn_mfma_f32_16x16x32_bf16(ah, bh[nt], acc[mt][nt], 0, 0, 0);
        acc[mt][nt] = __builtin_amdgcn_mfma_f32_16x16x32_bf16(ah, bl[nt], acc[mt][nt], 0, 0, 0);
        acc[mt][nt] = __builtin_amdgcn_mfma_f32_16x16x32_bf16(al, bh[nt], acc[mt][nt], 0, 0, 0);
      }
    }
    __syncthreads();
  }
  // epilogue: C layout col=lane&15, row=quad*4+reg
  const int qd = lane >> 4, cI = lane & 15;
  const int KCo = N >> 5;
  float* Cz = (MODE == 2) ? nullptr : (C + (size_t)z * sC);
  const char* Rhi = (MODE == 3) ? (Rpl + (size_t)z * sR) : nullptr;
  const char* Rlo = (MODE == 3) ? (Rhi + (size_t)N * 4096) : nullptr;
  char* Phi = (MODE == 2) ? (Ppl + (size_t)z * sP) : nullptr;
  char* Plo = (MODE == 2) ? (Phi + (size_t)N * 4096) : nullptr;
  #pragma unroll
  for (int mt = 0; mt < MT; ++mt) {
    #pragma unroll
    for (int nt = 0; nt < MT; ++nt) {
      int row0 = arow0 + (wm * MT + mt) * 16 + qd * 4;
      int col  = bcol0 + (wn * MT + nt) * 16 + cI;
      float bv = bz[col];
      #pragma unroll
      for (int r = 0; r < 4; ++r) {
        int row = row0 + r;
        float v = acc[mt][nt][r] + bv;
        if (MODE == 1) v += residF[(size_t)row * N + col];
        if (MODE == 3) {
          size_t ra = fbaddr(row, col, KCo);
          v += bf2f(*(const unsigned short*)(Rhi + ra))
             + bf2f(*(const unsigned short*)(Rlo + ra));
        }
        if (MODE == 2) {
          v = 0.5f * v * (1.0f + erff(v * 0.70710678118654752f));
          unsigned short hb = f2bf(v);
          unsigned short lb = f2bf(v - bf2f(hb));
          size_t pa = fbaddr(row, col, KCo);
          *(unsigned short*)(Phi + pa) = hb;
          *(unsigned short*)(Plo + pa) = lb;
        } else {
          Cz[(size_t)row * N + col] = v;
        }
      }
    }
  }
}

// ---------------------------------------------------------------------------
// Attention (fp32 VALU), path-batched: z in [0, 96*paths); path = z/96.
// qkv layout: [path][3][2048][768] fp32.
// ---------------------------------------------------------------------------
__global__ __launch_bounds__(256)
void attn_scores(const float* __restrict__ qkv, const float* __restrict__ mask,
                 float* __restrict__ sc,
                 const float* __restrict__ sel, int codeA, int codeB)
{
  const int z = blockIdx.z;
  const int path = z / 96, zz = z - path * 96;
  const int b = zz / NHq, hh = zz % NHq;
  const int code = path ? codeB : codeA;
  if (code && sel[b] != (float)code) return;
  const float* q = qkv + (size_t)path * 3 * BSH;
  const float* k = q + BSH;
  const long base = (long)b * Sq * Hq + hh * 64;
  const int im = blockIdx.y, in = blockIdx.x;
  const int tid = threadIdx.x;
  const int tx = tid & 15, ty = tid >> 4;
  __shared__ __align__(16) float Qs[16][68];
  __shared__ __align__(16) float Ks[16][68];
  float acc[4][4] = {};
  const int row = tid >> 2;
  const int kl = (tid & 3) << 2;
  for (int kt = 0; kt < 64; kt += 16) {
    float4 a4 = *(const float4*)(q + base + (long)(im * 64 + row) * Hq + kt + kl);
    Qs[kl + 0][row] = a4.x; Qs[kl + 1][row] = a4.y; Qs[kl + 2][row] = a4.z; Qs[kl + 3][row] = a4.w;
    float4 b4 = *(const float4*)(k + base + (long)(in * 64 + row) * Hq + kt + kl);
    Ks[kl + 0][row] = b4.x; Ks[kl + 1][row] = b4.y; Ks[kl + 2][row] = b4.z; Ks[kl + 3][row] = b4.w;
    __syncthreads();
    #pragma unroll
    for (int kk = 0; kk < 16; ++kk) {
      float a[4], bb[4];
      *(float4*)a = *(const float4*)&Qs[kk][ty * 4];
      *(float4*)bb = *(const float4*)&Ks[kk][tx * 4];
      #pragma unroll
      for (int i2 = 0; i2 < 4; ++i2)
        #pragma unroll
        for (int j2 = 0; j2 < 4; ++j2)
          acc[i2][j2] = fmaf(a[i2], bb[j2], acc[i2][j2]);
    }
    __syncthreads();
  }
  #pragma unroll
  for (int i2 = 0; i2 < 4; ++i2) {
    int ig = im * 64 + ty * 4 + i2;
    #pragma unroll
    for (int j2 = 0; j2 < 4; ++j2) {
      int jg = in * 64 + tx * 4 + j2;
      sc[(long)z * (Sq * Sq) + (long)ig * Sq + jg] = acc[i2][j2] * 0.125f + mask[b * Sq + jg];
    }
  }
}

__global__ __launch_bounds__(256)
void softmax256(float* __restrict__ sc, const float* __restrict__ sel,
                int codeA, int codeB)
{
  const int wid = threadIdx.x >> 6, lane = threadIdx.x & 63;
  const long row = (long)blockIdx.x * 4 + wid;
  const int z = (int)(row >> 8);
  const int path = z / 96, zz = z - path * 96;
  const int code = path ? codeB : codeA;
  if (code && sel[zz / NHq] != (float)code) return;
  float* p = sc + row * Sq;
  float v[4];
  float m = -1e30f;
  #pragma unroll
  for (int t = 0; t < 4; ++t) { v[t] = p[lane + t * 64]; m = fmaxf(m, v[t]); }
  #pragma unroll
  for (int off = 32; off >= 1; off >>= 1) m = fmaxf(m, __shfl_xor(m, off));
  float s = 0.0f;
  #pragma unroll
  for (int t = 0; t < 4; ++t) { v[t] = expf(v[t] - m); s += v[t]; }
  #pragma unroll
  for (int off = 32; off >= 1; off >>= 1) s += __shfl_xor(s, off);
  #pragma unroll
  for (int t = 0; t < 4; ++t) p[lane + t * 64] = v[t] / s;
}

// ctx -> FB16 planes; out per path at ctxpl + path*PLPAIR
__global__ __launch_bounds__(256)
void attn_ctx(const float* __restrict__ sc, const float* __restrict__ qkv,
              char* __restrict__ ctxpl,
              const float* __restrict__ sel, int codeA, int codeB)
{
  const int z = blockIdx.z;
  const int path = z / 96, zz = z - path * 96;
  const int b = zz / NHq, hh = zz % NHq;
  const int code = path ? codeB : codeA;
  if (code && sel[b] != (float)code) return;
  const float* P = sc + (long)z * (Sq * Sq);
  const float* V = qkv + (size_t)path * 3 * BSH + 2 * BSH + (long)b * Sq * Hq + hh * 64;
  char* Phi = ctxpl + (size_t)path * PLPAIR;
  char* Plo = Phi + PLH;
  const int im = blockIdx.y;
  const int tid = threadIdx.x;
  const int tx = tid & 15, ty = tid >> 4;
  __shared__ __align__(16) float Ps[16][68];
  __shared__ __align__(16) float Vs[16][64];
  float acc[4][4] = {};
  const int row = tid >> 2;
  const int kl = (tid & 3) << 2;
  const int vr = tid >> 4, vc = (tid & 15) << 2;
  for (int kt = 0; kt < Sq; kt += 16) {
    float4 a4 = *(const float4*)(P + (long)(im * 64 + row) * Sq + kt + kl);
    Ps[kl + 0][row] = a4.x; Ps[kl + 1][row] = a4.y; Ps[kl + 2][row] = a4.z; Ps[kl + 3][row] = a4.w;
    *(float4*)&Vs[vr][vc] = *(const float4*)(V + (long)(kt + vr) * Hq + vc);
    __syncthreads();
    #pragma unroll
    for (int kk = 0; kk < 16; ++kk) {
      float a[4], bb[4];
      *(float4*)a = *(const float4*)&Ps[kk][ty * 4];
      *(float4*)bb = *(const float4*)&Vs[kk][tx * 4];
      #pragma unroll
      for (int i2 = 0; i2 < 4; ++i2)
        #pragma unroll
        for (int j2 = 0; j2 < 4; ++j2)
          acc[i2][j2] = fmaf(a[i2], bb[j2], acc[i2][j2]);
    }
    __syncthreads();
  }
  const int c0 = hh * 64 + tx * 4;
  #pragma unroll
  for (int i2 = 0; i2 < 4; ++i2) {
    int grow = b * 256 + im * 64 + ty * 4 + i2;
    unsigned short h[4], l[4];
    #pragma unroll
    for (int j2 = 0; j2 < 4; ++j2) {
      float x = acc[i2][j2];
      h[j2] = f2bf(x);
      l[j2] = f2bf(x - bf2f(h[j2]));
    }
    size_t pa = fbaddr(grow, c0, 24);
    uint2 uh; uh.x = (unsigned)h[0] | ((unsigned)h[1] << 16); uh.y = (unsigned)h[2] | ((unsigned)h[3] << 16);
    uint2 ul; ul.x = (unsigned)l[0] | ((unsigned)l[1] << 16); ul.y = (unsigned)l[2] | ((unsigned)l[3] << 16);
    *(uint2*)(Phi + pa) = uh;
    *(uint2*)(Plo + pa) = ul;
  }
}

// ---------------------------------------------------------------------------
// LayerNorm (row of 768) -> FB16 planes, path-batched.
// ---------------------------------------------------------------------------
__global__ __launch_bounds__(256)
void ln2(const float* __restrict__ x, char* __restrict__ ypl,
         const float* __restrict__ gA, const float* __restrict__ bA,
         const float* __restrict__ gB, const float* __restrict__ bB,
         const float* __restrict__ sel, int codeA, int codeB)
{
  const int row = blockIdx.x, t = threadIdx.x;
  const int path = row >> 11;
  const int lrow = row & 2047;
  const int code = path ? codeB : codeA;
  if (code && sel[lrow >> 8] != (float)code) return;
  const float* g = path ? gB : gA;
  const float* bta = path ? bB : bA;
  const float* xr = x + (size_t)row * Hq;
  __shared__ float xs[Hq];
  __shared__ float ss[4], qq[4];
  float a = xr[t], b = xr[t + 256], c = xr[t + 512];
  xs[t] = a; xs[t + 256] = b; xs[t + 512] = c;
  float s = a + b + c;
  float q2 = a * a + b * b + c * c;
  #pragma unroll
  for (int off = 32; off >= 1; off >>= 1) { s += __shfl_xor(s, off); q2 += __shfl_xor(q2, off); }
  const int wid = t >> 6, lane = t & 63;
  if (lane == 0) { ss[wid] = s; qq[wid] = q2; }
  __syncthreads();
  s = ss[0] + ss[1] + ss[2] + ss[3];
  q2 = qq[0] + qq[1] + qq[2] + qq[3];
  const float mean = s * (1.0f / 768.0f);
  const float var = q2 * (1.0f / 768.0f) - mean * mean;
  const float r = rsqrtf(var + 1e-12f);
  if (t < 96) {
    const int c0 = t * 8;
    unsigned short hs[8], ls[8];
    #pragma unroll
    for (int j = 0; j < 8; ++j) {
      float y = (xs[c0 + j] - mean) * r * g[c0 + j] + bta[c0 + j];
      hs[j] = f2bf(y);
      ls[j] = f2bf(y - bf2f(hs[j]));
    }
    char* yh = ypl + (size_t)path * PLPAIR;
    char* yl = yh + PLH;
    size_t pa = fbaddr(lrow, c0, 24);
    *(uint4*)(yh + pa) = pack8(hs);
    *(uint4*)(yl + pa) = pack8(ls);
  }
}

// ---------------------------------------------------------------------------
// h0: copy fp32 + emit planes. grid 768 x 256.
// ---------------------------------------------------------------------------
__global__ __launch_bounds__(256)
void h0split(const float* __restrict__ src, float* __restrict__ hout,
             char* __restrict__ hh, char* __restrict__ hl)
{
  const int idx = blockIdx.x * 256 + threadIdx.x;
  const int row = idx / 96, c0 = (idx % 96) * 8;
  const float* p = src + (size_t)row * Hq + c0;
  float v[8];
  *(float4*)&v[0] = ((const float4*)p)[0];
  *(float4*)&v[4] = ((const float4*)p)[1];
  float* o = hout + (size_t)row * Hq + c0;
  ((float4*)o)[0] = *(float4*)&v[0];
  ((float4*)o)[1] = *(float4*)&v[4];
  unsigned short hs[8], ls[8];
  #pragma unroll
  for (int j = 0; j < 8; ++j) { hs[j] = f2bf(v[j]); ls[j] = f2bf(v[j] - bf2f(hs[j])); }
  size_t pa = fbaddr(row, c0, 24);
  *(uint4*)(hh + pa) = pack8(hs);
  *(uint4*)(hl + pa) = pack8(ls);
}

// ---------------------------------------------------------------------------
// Select: h = (code==1)?base:(code==2)?large:h ; refresh fp32 + planes
// ---------------------------------------------------------------------------
__global__ __launch_bounds__(256)
void select_fb(float* __restrict__ hout, char* __restrict__ hh, char* __restrict__ hl,
               const char* __restrict__ bh, const char* __restrict__ bl,
               const char* __restrict__ gh, const char* __restrict__ gl,
               const float* __restrict__ sel)
{
  const int idx = blockIdx.x * 256 + threadIdx.x;
  const int row = idx / 96, c0 = (idx % 96) * 8;
  const int b = row >> 8;
  const float code = sel[b];
  const size_t pa = fbaddr(row, c0, 24);
  float v[8];
  if (code == 1.0f || code == 2.0f) {
    const char* sh = (code == 1.0f) ? bh : gh;
    const char* sl = (code == 1.0f) ? bl : gl;
    uint4 H = *(const uint4*)(sh + pa);
    uint4 L = *(const uint4*)(sl + pa);
    const unsigned* hw = (const unsigned*)&H;
    const unsigned* lw = (const unsigned*)&L;
    #pragma unroll
    for (int j = 0; j < 8; ++j) {
      unsigned short hb = (unsigned short)(hw[j >> 1] >> ((j & 1) * 16));
      unsigned short lb = (unsigned short)(lw[j >> 1] >> ((j & 1) * 16));
      v[j] = bf2f(hb) + bf2f(lb);
    }
  } else {
    const float* p = hout + (size_t)row * Hq + c0;
    *(float4*)&v[0] = ((const float4*)p)[0];
    *(float4*)&v[4] = ((const float4*)p)[1];
  }
  float* o = hout + (size_t)row * Hq + c0;
  ((float4*)o)[0] = *(float4*)&v[0];
  ((float4*)o)[1] = *(float4*)&v[4];
  unsigned short hs[8], ls[8];
  #pragma unroll
  for (int j = 0; j < 8; ++j) { hs[j] = f2bf(v[j]); ls[j] = f2bf(v[j] - bf2f(hs[j])); }
  *(uint4*)(hh + pa) = pack8(hs);
  *(uint4*)(hl + pa) = pack8(ls);
}

// ---------------------------------------------------------------------------
// Router phase 1: pooled = tanh(h_cls @ pw + pb) for A (mat=0) and E (mat=1).
// Grid (12, Bq, 2) x 64 threads. Thread t computes col c = bx*64+t with the
// EXACT serial r=0..767 fmaf chain (bit-identical to the monolithic router).
// pooled layout: [mat][b][768] fp32.
// ---------------------------------------------------------------------------
__global__ __launch_bounds__(64)
void router_pool(const float* __restrict__ h,
                 const float* __restrict__ A_pw, const float* __restrict__ A_pb,
                 const float* __restrict__ E_pw, const float* __restrict__ E_pb,
                 const float* __restrict__ active,
                 float* __restrict__ pooled)
{
  const int b = blockIdx.y, mat = blockIdx.z;
  if (active[b] == 0.0f) return;
  const float* pw = mat ? E_pw : A_pw;
  const float* pb = mat ? E_pb : A_pb;
  const int c = blockIdx.x * 64 + threadIdx.x;
  const float* hc = h + (size_t)b * Sq * Hq;
  float s = pb[c];
  for (int r = 0; r < Hq; ++r)
    s = fmaf(hc[r], pw[(size_t)r * Hq + c], s);
  pooled[((size_t)mat * Bq + b) * Hq + c] = tanhf(s);
}

// ---------------------------------------------------------------------------
// Router phase 2: classifier dots + softmax + routing decision. Grid Bq x 256.
// Reduction order identical to the previous passing router.
// ---------------------------------------------------------------------------
__global__ __launch_bounds__(256)
void router_decide(const float* __restrict__ pooled,
                   const float* __restrict__ A_cw, const float* __restrict__ A_cb,
                   const float* __restrict__ E_cw, const float* __restrict__ E_cb,
                   float* __restrict__ active,
                   float* __restrict__ probs_out, float* __restrict__ acts_out,
                   float* __restrict__ exit_logits, float* __restrict__ exit_part,
                   float* __restrict__ sel_code, int part)
{
  const int b = blockIdx.x, t = threadIdx.x;
  const bool act = (active[b] != 0.0f);
  if (!act) {
    if (t == 0) {
      probs_out[b * 3 + 0] = 1.0f;
      probs_out[b * 3 + 1] = 1.0f;
      probs_out[b * 3 + 2] = 1.0f;
      acts_out[b] = 0.0f;
      sel_code[b] = 0.0f;
    }
    return;
  }
  __shared__ float red[3][256];
  __shared__ float resL[3];
  const float* pA = pooled + (size_t)b * Hq;
  const float* pE = pooled + (size_t)(Bq + b) * Hq;
  {
    float p0 = 0, p1 = 0, p2 = 0;
    for (int r = t; r < Hq; r += 256) {
      float p = pA[r];
      p0 = fmaf(p, A_cw[r * 3 + 0], p0);
      p1 = fmaf(p, A_cw[r * 3 + 1], p1);
      p2 = fmaf(p, A_cw[r * 3 + 2], p2);
    }
    red[0][t] = p0; red[1][t] = p1; red[2][t] = p2;
  }
  __syncthreads();
  for (int s2 = 128; s2 > 0; s2 >>= 1) {
    if (t < s2) { red[0][t] += red[0][t + s2]; red[1][t] += red[1][t + s2]; red[2][t] += red[2][t + s2]; }
    __syncthreads();
  }
  if (t == 0) { resL[0] = red[0][0] + A_cb[0]; resL[1] = red[1][0] + A_cb[1]; resL[2] = red[2][0] + A_cb[2]; }
  __syncthreads();
  {
    float p0 = 0, p1 = 0;
    for (int r = t; r < Hq; r += 256) {
      float p = pE[r];
      p0 = fmaf(p, E_cw[r * 2 + 0], p0);
      p1 = fmaf(p, E_cw[r * 2 + 1], p1);
    }
    red[0][t] = p0; red[1][t] = p1;
  }
  __syncthreads();
  for (int s2 = 128; s2 > 0; s2 >>= 1) {
    if (t < s2) { red[0][t] += red[0][t + s2]; red[1][t] += red[1][t + s2]; }
    __syncthreads();
  }
  if (t == 0) {
    const float e0 = red[0][0] + E_cb[0], e1 = red[1][0] + E_cb[1];
    const float l0 = resL[0], l1 = resL[1], l2 = resL[2];
    int action = 0; float bv = l0;
    if (l1 > bv) { bv = l1; action = 1; }
    if (l2 > bv) { bv = l2; action = 2; }
    const float x0 = expf(l0 - bv), x1 = expf(l1 - bv), x2 = expf(l2 - bv);
    const float ssum = x0 + x1 + x2;
    probs_out[b * 3 + 0] = x0 / ssum;
    probs_out[b * 3 + 1] = x1 / ssum;
    probs_out[b * 3 + 2] = x2 / ssum;
    acts_out[b] = (float)action;
    if (action == 0) {
      exit_logits[b * 2 + 0] = e0;
      exit_logits[b * 2 + 1] = e1;
      exit_part[b] = (float)part;
    }
    sel_code[b] = (float)action;
    active[b] = (action != 0) ? 1.0f : 0.0f;
  }
}

__global__ __launch_bounds__(64)
void init_kernel(float* __restrict__ active, float* __restrict__ exit_logits,
                 float* __restrict__ exit_part)
{
  const int t = threadIdx.x;
  if (t < 8) { active[t] = 1.0f; exit_part[t] = -1.0f; }
  if (t < 16) exit_logits[t] = 0.0f;
}

// ---------------------------------------------------------------------------
extern "C" void kernel_launch(void* const* d_in, const int* in_sizes, int n_in,
                              void* d_out, int out_size, void* d_ws, size_t ws_size,
                              hipStream_t stream)
{
  (void)in_sizes; (void)n_in; (void)out_size;
  const float* hidden   = (const float*)d_in[0];
  const float* mask     = (const float*)d_in[1];
  const float* L_attn_w = (const float*)d_in[2];
  const float* L_attn_b = (const float*)d_in[3];
  const float* L_ln_g   = (const float*)d_in[4];
  const float* L_ln_b   = (const float*)d_in[5];
  const float* L_wi     = (const float*)d_in[6];
  const float* L_bi     = (const float*)d_in[7];
  const float* L_wo     = (const float*)d_in[8];
  const float* L_bo     = (const float*)d_in[9];
  const float* S_attn_w = (const float*)d_in[10];
  const float* S_attn_b = (const float*)d_in[11];
  const float* S_ln_g   = (const float*)d_in[12];
  const float* S_ln_b   = (const float*)d_in[13];
  const float* S_wi     = (const float*)d_in[14];
  const float* S_bi     = (const float*)d_in[15];
  const float* S_wo     = (const float*)d_in[16];
  const float* S_bo     = (const float*)d_in[17];
  const float* E_pw     = (const float*)d_in[18];
  const float* E_pb     = (const float*)d_in[19];
  const float* E_cw     = (const float*)d_in[20];
  const float* E_cb     = (const float*)d_in[21];
  const float* A_pw     = (const float*)d_in[22];
  const float* A_pb     = (const float*)d_in[23];
  const float* A_cw     = (const float*)d_in[24];
  const float* A_cb     = (const float*)d_in[25];

  float* out = (float*)d_out;
  float* h      = out;
  float* active = out + 1572864;
  float* probs  = out + 1572872;
  float* acts   = out + 1573016;
  float* exitl  = out + 1573064;
  float* exitp  = out + 1573080;

  char* ws = (char*)d_ws;
  float* sel    = (float*)ws;               // 256 B
  float* pooled = (float*)(ws + 256);       // 2*8*768 fp32 = 49152 B
  char* hpl     = ws + 256 + 49152;
  char* basepl  = hpl + PLPAIR;
  char* j0pl    = basepl + PLPAIR;          // contiguous after basepl (LN2 s1)
  char* largepl = j0pl + PLPAIR;
  char* ctxpl   = largepl + PLPAIR;
  char* qkvreg  = ctxpl + 2 * PLPAIR;       // 37,748,736 B (6 fp32 slots)
  char* big     = qkvreg + 37748736L;       // 50,331,648 B
  char* warena  = big + 50331648L;
  const size_t actBytes = (size_t)(warena - ws);
  const bool full = ws_size >= actBytes + 18ULL * SLOTW;

  // overlays
  float* qkv    = (float*)qkvreg;
  char*  x1pl   = qkvreg;                   // after qkv q/k dead (post-ctx)
  float* t2     = (float*)(qkvreg + 2 * PLPAIR);
  float* scores = (float*)big;
  float* Oout   = (float*)big;              // after scores dead (post-ctx)
  char*  ffnpl  = big;                      // after Oout dead (post-LN1)

  // weight arena regions (JIT fallback)
  char* R1a = warena;
  char* R1b = warena + 9437184L;
  char* R2a = warena + 18874368L;
  char* R2b = warena + 28311552L;

  init_kernel<<<dim3(1), 64, 0, stream>>>(active, exitl, exitp);
  h0split<<<dim3(768), 256, 0, stream>>>(hidden, h, hpl, hpl + PLH);

  if (full) {
    // Convert ALL weights once: slots 0..11 = L layers, 12..17 = S layers.
    prep_w<<<dim3(12, 24, 48), 256, 0, stream>>>(L_attn_w, warena,
        768, 768, 589824L, 2359296L, 4, MATATTN, SLOTW, sel, 0);
    prep_w<<<dim3(12, 24, 24), 256, 0, stream>>>(S_attn_w, warena + 12 * SLOTW,
        768, 768, 589824L, 2359296L, 4, MATATTN, SLOTW, sel, 0);
    prep_w<<<dim3(48, 24, 12), 256, 0, stream>>>(L_wi, warena + WIOFF,
        768, 3072, 0L, 2359296L, 1, 0L, SLOTW, sel, 0);
    prep_w<<<dim3(48, 24, 6), 256, 0, stream>>>(S_wi, warena + 12 * SLOTW + WIOFF,
        768, 3072, 0L, 2359296L, 1, 0L, SLOTW, sel, 0);
    prep_w<<<dim3(12, 96, 12), 256, 0, stream>>>(L_wo, warena + WOOFF,
        3072, 768, 0L, 2359296L, 1, 0L, SLOTW, sel, 0);
    prep_w<<<dim3(12, 96, 6), 256, 0, stream>>>(S_wo, warena + 12 * SLOTW + WOOFF,
        3072, 768, 0L, 2359296L, 1, 0L, SLOTW, sel, 0);
  }

  for (int i = 0; i < 6; ++i) {
    const int j0 = 2 * i, j1 = 2 * i + 1;
    // weight plane pointers per tier
    const char *attnA, *attnB, *wiA, *wiB, *woA, *woB, *attnJ1, *wiJ1, *woJ1;
    if (full) {
      const char* sS  = warena + (12 + i) * SLOTW;
      const char* sL0 = warena + (size_t)j0 * SLOTW;
      const char* sL1 = warena + (size_t)j1 * SLOTW;
      attnA = sS;  wiA = sS + WIOFF;  woA = sS + WOOFF;
      attnB = sL0; wiB = sL0 + WIOFF; woB = sL0 + WOOFF;
      attnJ1 = sL1; wiJ1 = sL1 + WIOFF; woJ1 = sL1 + WOOFF;
    } else {
      attnA = R1a; attnB = R1b; wiA = R2a; wiB = R2b;
      woA = R1a; woB = R1b; attnJ1 = R2a; wiJ1 = R1a; woJ1 = R1b;
    }
    // biases / LN params
    const float* qkvBA = S_attn_b + (long)i * 4 * Hq;
    const float* qkvBB = L_attn_b + (long)j0 * 4 * Hq;
    const float* oBA   = qkvBA + 3 * Hq;
    const float* oBB   = qkvBB + 3 * Hq;
    const float* biA   = S_bi + (long)i * FFq;
    const float* biB   = L_bi + (long)j0 * FFq;
    const float* boA   = S_bo + (long)i * Hq;
    const float* boB   = L_bo + (long)j0 * Hq;
    const float* lgA   = S_ln_g + (long)i * 2 * Hq;
    const float* lbA   = S_ln_b + (long)i * 2 * Hq;
    const float* lgB   = L_ln_g + (long)j0 * 2 * Hq;
    const float* lbB   = L_ln_b + (long)j0 * 2 * Hq;
    const float* qkvB1 = L_attn_b + (long)j1 * 4 * Hq;
    const float* oB1   = qkvB1 + 3 * Hq;
    const float* bi1   = L_bi + (long)j1 * FFq;
    const float* bo1   = L_bo + (long)j1 * Hq;
    const float* lg1   = L_ln_g + (long)j1 * 2 * Hq;
    const float* lb1   = L_ln_b + (long)j1 * 2 * Hq;

    router_pool<<<dim3(12, Bq, 2), 64, 0, stream>>>(
        h, A_pw, A_pb, E_pw + (long)i * Hq * Hq, E_pb + i * Hq, active, pooled);
    router_decide<<<dim3(Bq), 256, 0, stream>>>(
        pooled, A_cw, A_cb, E_cw + (long)i * Hq * 2, E_cb + i * 2,
        active, probs + i * 24, acts + i * 8, exitl, exitp, sel, i);

    if (!full) {
      prep_w<<<dim3(12, 24, 4), 256, 0, stream>>>(S_attn_w + (long)i * 4 * Hq * Hq, R1a,
          768, 768, 589824L, 0L, 4, MATATTN, 0L, sel, 1);
      prep_w<<<dim3(12, 24, 4), 256, 0, stream>>>(L_attn_w + (long)j0 * 4 * Hq * Hq, R1b,
          768, 768, 589824L, 0L, 4, MATATTN, 0L, sel, 2);
      prep_w<<<dim3(48, 24, 1), 256, 0, stream>>>(S_wi + (long)i * Hq * FFq, R2a,
          768, 3072, 0L, 0L, 1, 0L, 0L, sel, 1);
      prep_w<<<dim3(48, 24, 1), 256, 0, stream>>>(L_wi + (long)j0 * Hq * FFq, R2b,
          768, 3072, 0L, 0L, 1, 0L, 0L, sel, 2);
    }

    // ---------------- stage 1: base (path A, code 1) + large j0 (path B, code 2)
    gemm_fb<2, 0><<<dim3(12, 32, 6), 256, 0, stream>>>(
        hpl, 0L, attnA, attnB, 3, MATATTN, qkvBA, qkvBB, (long)Hq,
        nullptr, nullptr, 0L, qkv, (long)BSH, nullptr, 0L,
        768, 768, sel, 1, 2);
    attn_scores<<<dim3(4, 4, 192), 256, 0, stream>>>(qkv, mask, scores, sel, 1, 2);
    softmax256<<<dim3(192 * 64), 256, 0, stream>>>(scores, sel, 1, 2);
    attn_ctx<<<dim3(1, 4, 192), 256, 0, stream>>>(scores, qkv, ctxpl, sel, 1, 2);
    gemm_fb<2, 1><<<dim3(12, 32, 2), 256, 0, stream>>>(
        ctxpl, PLPAIR, attnA + 3 * MATATTN, attnB + 3 * MATATTN, 1, 0L,
        oBA, oBB, 0L, h, nullptr, 0L, Oout, (long)BSH, nullptr, 0L,
        768, 768, sel, 1, 2);
    if (!full) {
      prep_w<<<dim3(12, 96, 1), 256, 0, stream>>>(S_wo + (long)i * FFq * Hq, R1a,
          3072, 768, 0L, 0L, 1, 0L, 0L, sel, 1);
      prep_w<<<dim3(12, 96, 1), 256, 0, stream>>>(L_wo + (long)j0 * FFq * Hq, R1b,
          3072, 768, 0L, 0L, 1, 0L, 0L, sel, 2);
    }
    ln2<<<dim3(4096), 256, 0, stream>>>(Oout, x1pl, lgA, lbA, lgB, lbB, sel, 1, 2);
    gemm_fb<4, 2><<<dim3(24, 16, 2), 256, 0, stream>>>(
        x1pl, PLPAIR, wiA, wiB, 1, 0L, biA, biB, 0L,
        nullptr, nullptr, 0L, nullptr, 0L, ffnpl, 25165824L,
        3072, 768, sel, 1, 2);
    if (!full)
      prep_w<<<dim3(12, 24, 4), 256, 0, stream>>>(L_attn_w + (long)j1 * 4 * Hq * Hq, R2a,
          768, 768, 589824L, 0L, 4, MATATTN, 0L, sel, 2);
    gemm_fb<2, 3><<<dim3(12, 32, 2), 256, 0, stream>>>(
        ffnpl, 25165824L, woA, woB, 1, 0L, boA, boB, 0L,
        nullptr, x1pl, PLPAIR, t2, (long)BSH, nullptr, 0L,
        768, 3072, sel, 1, 2);
    if (!full) {
      prep_w<<<dim3(48, 24, 1), 256, 0, stream>>>(L_wi + (long)j1 * Hq * FFq, R1a,
          768, 3072, 0L, 0L, 1, 0L, 0L, sel, 2);
      prep_w<<<dim3(12, 96, 1), 256, 0, stream>>>(L_wo + (long)j1 * FFq * Hq, R1b,
          3072, 768, 0L, 0L, 1, 0L, 0L, sel, 2);
    }
    ln2<<<dim3(4096), 256, 0, stream>>>(t2, basepl, lgA + Hq, lbA + Hq,
                                        lgB + Hq, lbB + Hq, sel, 1, 2);

    // ---------------- stage 2: large j1 (single path, code 2), input j0pl
    gemm_fb<2, 0><<<dim3(12, 32, 3), 256, 0, stream>>>(
        j0pl, 0L, attnJ1, attnJ1, 3, MATATTN, qkvB1, qkvB1, (long)Hq,
        nullptr, nullptr, 0L, qkv, (long)BSH, nullptr, 0L,
        768, 768, sel, 2, 2);
    attn_scores<<<dim3(4, 4, 96), 256, 0, stream>>>(qkv, mask, scores, sel, 2, 2);
    softmax256<<<dim3(96 * 64), 256, 0, stream>>>(scores, sel, 2, 2);
    attn_ctx<<<dim3(1, 4, 96), 256, 0, stream>>>(scores, qkv, ctxpl, sel, 2, 2);
    gemm_fb<2, 3><<<dim3(12, 32, 1), 256, 0, stream>>>(
        ctxpl, PLPAIR, attnJ1 + 3 * MATATTN, attnJ1 + 3 * MATATTN, 1, 0L,
        oB1, oB1, 0L, nullptr, j0pl, 0L, Oout, (long)BSH, nullptr, 0L,
        768, 768, sel, 2, 2);
    ln2<<<dim3(2048), 256, 0, stream>>>(Oout, x1pl, lg1, lb1, lg1, lb1, sel, 2, 2);
    gemm_fb<4, 2><<<dim3(24, 16, 1), 256, 0, stream>>>(
        x1pl, PLPAIR, wiJ1, wiJ1, 1, 0L, bi1, bi1, 0L,
        nullptr, nullptr, 0L, nullptr, 0L, ffnpl, 25165824L,
        3072, 768, sel, 2, 2);
    gemm_fb<2, 3><<<dim3(12, 32, 1), 256, 0, stream>>>(
        ffnpl, 25165824L, woJ1, woJ1, 1, 0L, bo1, bo1, 0L,
        nullptr, x1pl, PLPAIR, t2, (long)BSH, nullptr, 0L,
        768, 3072, sel, 2, 2);
    ln2<<<dim3(2048), 256, 0, stream>>>(t2, largepl, lg1 + Hq, lb1 + Hq,
                                        lg1 + Hq, lb1 + Hq, sel, 2, 2);

    select_fb<<<dim3(768), 256, 0, stream>>>(h, hpl, hpl + PLH,
                                             basepl, basepl + PLH,
                                             largepl, largepl + PLH, sel);
  }
}